// Round 11
// baseline (2111.860 us; speedup 1.0000x reference)
//
#include <hip/hip_runtime.h>
#include <hip/hip_fp16.h>

#define B_   64
#define NB   128
#define E_   1024
#define DH   300
#define G3   900
#define OUTD 1924
#define SLICES 4
#define PK_STRIDE 1800
#define MROW 160   // u64/row: u32 data words [0..149], tag u64s [152..159]
#define KP_LDS 42  // weight kp-pairs staged in LDS
#define WL_STR 456 // LDS weight slab row stride (>= 450 rows, bank-friendly)

typedef _Float16 h2raw __attribute__((ext_vector_type(2)));

__device__ __forceinline__ float dot2f(unsigned int m2, unsigned int w, float acc) {
    h2raw a, b;
    __builtin_memcpy(&a, &m2, 4);
    __builtin_memcpy(&b, &w, 4);
    return __builtin_amdgcn_fdot2(a, b, acc, false);
}

__device__ __forceinline__ unsigned int packh2(float x, float y) {
    __half2 h;
    h.x = __float2half_rn(x);
    h.y = __float2half_rn(y);
    unsigned int u;
    __builtin_memcpy(&u, &h, 4);
    return u;
}

__device__ __forceinline__ float sigmoidf_(float x) { return 1.f / (1.f + __expf(-x)); }
__device__ __forceinline__ float tanh_fast(float x) { return 1.f - 2.f / (__expf(2.f * x) + 1.f); }

// ---------------- copy features into output tail ----------------
__global__ __launch_bounds__(256)
void copy_feat(const float* __restrict__ f, float* __restrict__ out) {
    const long id = (long)blockIdx.x * 256 + threadIdx.x;
    const long r = id >> 8;
    const int  c = (int)(id & 255);
    const float4 v = ((const float4*)(f + r * E_))[c];
    ((float4*)(out + r * OUTD + 3 * DH))[c] = v;
}

// ---------------- pack recurrent weights -> PK2[l][kp(150)][R(1800)] f16-pairs (kp-major) ----------------
__global__ __launch_bounds__(256)
void pack2(const float* __restrict__ gc_whh, const float* __restrict__ gp_wih,
           unsigned int* __restrict__ dst) {
    const int id = blockIdx.x * 256 + threadIdx.x;
    if (id >= 2 * 150 * PK_STRIDE) return;
    const int l   = id / (150 * PK_STRIDE);
    const int rem = id % (150 * PK_STRIDE);
    const int kp  = rem / PK_STRIDE;
    const int R   = rem % PK_STRIDE;
    const int mat = R / G3;
    const int o   = R % G3;
    const float* W = (mat ? gp_wih : gc_whh) + (long)l * G3 * DH;
    const float2 v = *(const float2*)(W + (long)o * DH + 2 * kp);
    dst[id] = packh2(v.x, v.y);
}

// ---------------- GEMM input packing to f16 pairs ----------------
__global__ __launch_bounds__(256)
void pack_af(const float* __restrict__ src, unsigned int* __restrict__ dst) {
    const long id = (long)blockIdx.x * 256 + threadIdx.x;   // 8192*512
    const long r = id >> 9;
    const int kp = (int)(id & 511);
    const float2 v = *(const float2*)(src + r * E_ + 2 * kp);
    dst[id] = packh2(v.x, v.y);
}

__global__ __launch_bounds__(256)
void pack_ah(const float* __restrict__ src, unsigned int* __restrict__ dst) {
    const long id = (long)blockIdx.x * 256 + threadIdx.x;   // 8192*160
    const long r = id / 160;
    const int kp = (int)(id % 160);
    unsigned int u = 0u;
    if (kp < 150) {
        const float2 v = *(const float2*)(src + r * OUTD + 2 * kp);
        u = packh2(v.x, v.y);
    }
    dst[id] = u;
}

__global__ __launch_bounds__(256)
void pack_bf(const float* __restrict__ W, unsigned int* __restrict__ dst) {
    const int id = blockIdx.x * 256 + threadIdx.x;          // 320*512
    const int n = id >> 9;
    const int kp = id & 511;
    unsigned int u = 0u;
    if (n < DH) u = packh2(W[(2 * kp) * DH + n], W[(2 * kp + 1) * DH + n]);
    dst[id] = u;
}

__global__ __launch_bounds__(256)
void pack_bw(const float* __restrict__ W, unsigned int* __restrict__ dst) {
    const int id = blockIdx.x * 256 + threadIdx.x;          // 960*160
    const int n = id / 160;
    const int kp = id % 160;
    unsigned int u = 0u;
    if (n < G3 && kp < 150) {
        const float2 v = *(const float2*)(W + (long)n * DH + 2 * kp);
        u = packh2(v.x, v.y);
    }
    dst[id] = u;
}

// ---------------- f16-dot2 GEMM ----------------
template<int RELU>
__global__ __launch_bounds__(256)
void gemm_h16(const unsigned int* __restrict__ APK, int ldap,
              const unsigned int* __restrict__ BPK, int ldbp,
              const float* __restrict__ bias,
              float* __restrict__ C, int ldc,
              int N, int KP)
{
    __shared__ __align__(16) unsigned int As[16][132];
    __shared__ __align__(16) unsigned int Bs[16][68];
    const int tid = threadIdx.x;
    const int m0 = blockIdx.y * 128;
    const int n0 = blockIdx.x * 64;
    const int tx = tid & 15, ty = tid >> 4;
    const int am = tid >> 1, ak8 = (tid & 1) * 8;
    const int bn = tid >> 2, bk4 = (tid & 3) * 4;

    float acc[8][4] = {{0.f}};
    const unsigned int* ap = APK + (long)(m0 + am) * ldap + ak8;
    const unsigned int* bp = BPK + (long)(n0 + bn) * ldbp + bk4;

    for (int kp0 = 0; kp0 < KP; kp0 += 16) {
        const uint4 a0 = *(const uint4*)(ap + kp0);
        const uint4 a1 = *(const uint4*)(ap + kp0 + 4);
        const uint4 bq = *(const uint4*)(bp + kp0);
        As[ak8 + 0][am] = a0.x; As[ak8 + 1][am] = a0.y;
        As[ak8 + 2][am] = a0.z; As[ak8 + 3][am] = a0.w;
        As[ak8 + 4][am] = a1.x; As[ak8 + 5][am] = a1.y;
        As[ak8 + 6][am] = a1.z; As[ak8 + 7][am] = a1.w;
        Bs[bk4 + 0][bn] = bq.x; Bs[bk4 + 1][bn] = bq.y;
        Bs[bk4 + 2][bn] = bq.z; Bs[bk4 + 3][bn] = bq.w;
        __syncthreads();
        #pragma unroll
        for (int kp = 0; kp < 16; ++kp) {
            const uint4 aA = *(const uint4*)&As[kp][ty * 8];
            const uint4 aB = *(const uint4*)&As[kp][ty * 8 + 4];
            const uint4 bb = *(const uint4*)&Bs[kp][tx * 4];
            const unsigned int av[8] = {aA.x, aA.y, aA.z, aA.w, aB.x, aB.y, aB.z, aB.w};
            const unsigned int bv[4] = {bb.x, bb.y, bb.z, bb.w};
            #pragma unroll
            for (int ii = 0; ii < 8; ++ii)
                #pragma unroll
                for (int jj = 0; jj < 4; ++jj)
                    acc[ii][jj] = dot2f(av[ii], bv[jj], acc[ii][jj]);
        }
        __syncthreads();
    }

    const int gn0 = n0 + tx * 4;
    #pragma unroll
    for (int ii = 0; ii < 8; ++ii) {
        const int gm = m0 + ty * 8 + ii;
        float* cp = C + (long)gm * ldc + gn0;
        if (gn0 + 3 < N) {
            const float4 bb = *(const float4*)&bias[gn0];
            float4 o;
            o.x = acc[ii][0] + bb.x; o.y = acc[ii][1] + bb.y;
            o.z = acc[ii][2] + bb.z; o.w = acc[ii][3] + bb.w;
            if (RELU) { o.x = fmaxf(o.x, 0.f); o.y = fmaxf(o.y, 0.f); o.z = fmaxf(o.z, 0.f); o.w = fmaxf(o.w, 0.f); }
            *(float4*)cp = o;
        } else if (gn0 < N) {
            for (int jj = 0; jj < 4; ++jj) {
                const int gn = gn0 + jj;
                if (gn < N) {
                    float v = acc[ii][jj] + bias[gn];
                    if (RELU) v = fmaxf(v, 0.f);
                    cp[jj] = v;
                }
            }
        }
    }
}

// ---------------- DAG scan v11: scan9 structure; weights = LDS slab (kp 0..41) + L2 stream (kp 42..149) ----------------
__global__ __launch_bounds__(512, 2)
void scan11(float* __restrict__ out,
            const float* __restrict__ GIC,
            const float* __restrict__ GHP,
            const unsigned int* __restrict__ PK2L,  // kp-major [150][1800]
            const float* __restrict__ cbhh,
            const float* __restrict__ pbih,
            const int* __restrict__ adj,
            const float* __restrict__ wk,
            unsigned long long* __restrict__ TBL,
            int l)
{
    extern __shared__ unsigned int histp[];   // [128][152] f16-pairs, then wlds [42][456]
    unsigned int* wlds = histp + 128 * 152;
    __shared__ float wsm2[NB];
    __shared__ float betas[NB];
    __shared__ float Mlds[DH];
    __shared__ __align__(16) unsigned int M2[152];
    __shared__ float gmv[456];
    __shared__ float mx2s, S_pres;

    const int tid = threadIdx.x;
    const int lane = tid & 63;
    const int wid = tid >> 6;
    const int b = blockIdx.x & 63;
    const int k = blockIdx.x >> 6;
    const int swk = (k == 3) ? 72 : 76;

    float* outb = out + (long)b * NB * OUTD;
    const float* xcol = outb + l * DH;
    float* ycol = outb + (l + 1) * DH;
    const float* gicb = GIC + (long)b * NB * G3;
    const float* ghpb = GHP + (long)b * NB * G3;
    const int* adjb = adj + b * NB * NB;
    unsigned long long* mb = TBL + (long)b * NB * MROW;
    unsigned int* mb32 = (unsigned int*)mb;

    if (tid < 152) M2[tid] = 0u;

    const int D = 76 * k + ((tid < swk) ? tid : 0);
    const float cb0 = cbhh[D], cb1 = cbhh[DH + D], cb2 = cbhh[2 * DH + D];
    const float pb0 = pbih[D], pb1 = pbih[DH + D], pb2 = pbih[2 * DH + D];
    const float wkD = wk[D];

    const int ROWS = 6 * swk;
    int R;
    {
        const int t = (tid < ROWS) ? tid : 0;
        const int d = t % swk;
        const int r = t / swk;
        R = (r / 3) * G3 + (r % 3) * DH + 76 * k + d;
    }

    // ---- stage kp-slab 0..41 of this slice's weight rows into LDS (once) ----
    for (int e = tid; e < KP_LDS * WL_STR; e += 512) {
        const int kp = e / WL_STR;
        const int rl = e % WL_STR;
        unsigned int v = 0u;
        if (rl < ROWS) {
            const int mat  = rl / (3 * swk);
            const int rest = rl % (3 * swk);
            const int gate = rest / swk;
            const int d    = rest % swk;
            v = PK2L[kp * PK_STRIDE + mat * G3 + gate * DH + 76 * k + d];
        }
        wlds[e] = v;
    }

    __syncthreads();

    const bool isv = (tid >= 256) && (tid < 406);
    const int vt = tid - 256;

    for (int i = 0; i < NB; ++i) {
        // ---- top-of-step prefetches ----
        float gi0 = 0, gi1 = 0, gi2 = 0, gp0 = 0, gp1 = 0, gp2 = 0, xi = 0;
        if (tid < swk) {
            const float* gic = gicb + (long)i * G3;
            const float* ghp = ghpb + (long)i * G3;
            gi0 = gic[D]; gi1 = gic[DH + D]; gi2 = gic[2 * DH + D];
            gp0 = ghp[D]; gp1 = ghp[DH + D]; gp2 = ghp[2 * DH + D];
            xi = xcol[(long)i * OUTD + D];
        }
        int a0p = 0, a1p = 0;
        if (wid == 2 && i + 1 < NB) {
            a0p = adjb[(i + 1) * NB + lane];
            a1p = adjb[(i + 1) * NB + 64 + lane];
        }

        if (i > 0) {
            float V0 = 0.f, V1 = 0.f;
            if (wid == 0) {
                // ---- poll 8 self-describing tag words ----
                const unsigned long long* trow = mb + (long)(i - 1) * MROW;
                const unsigned int tag = (unsigned int)i;
                const bool act = (lane < 8);
                unsigned long long tv = 0;
                while (true) {
                    if (act && (unsigned int)tv != tag)
                        tv = __hip_atomic_load(&trow[152 + lane],
                                               __ATOMIC_RELAXED, __HIP_MEMORY_SCOPE_AGENT);
                    if (__all(!act || (unsigned int)tv == tag)) break;
                }
                float bp = 0.f;
                if (act) {
                    const unsigned int hb = (unsigned int)(tv >> 32);
                    __builtin_memcpy(&bp, &hb, 4);
                }
                bp += __shfl_xor(bp, 1);
                bp += __shfl_xor(bp, 2);
                bp += __shfl_xor(bp, 4);
                if (lane == 0) betas[i - 1] = __shfl(bp, 0);

                unsigned long long d0 = 0, d1 = 0;
                if (lane < 38) {
                    d0 = __hip_atomic_load(&trow[2 * lane],
                                           __ATOMIC_RELAXED, __HIP_MEMORY_SCOPE_AGENT);
                    d1 = __hip_atomic_load(&trow[2 * lane + 1],
                                           __ATOMIC_RELAXED, __HIP_MEMORY_SCOPE_AGENT);
                    uint4 q;
                    q.x = (unsigned int)d0; q.y = (unsigned int)(d0 >> 32);
                    q.z = (unsigned int)d1; q.w = (unsigned int)(d1 >> 32);
                    *(uint4*)&histp[(i - 1) * 152 + 4 * lane] = q;
                }
            } else if (isv) {
                // ---- V-loop over j <= i-2 with precomputed unnormalized weights ----
                #pragma unroll 4
                for (int j = 0; j + 1 < i; ++j) {
                    const float wj = wsm2[j];
                    const unsigned int u = histp[j * 152 + vt];
                    __half2 h; __builtin_memcpy(&h, &u, 4);
                    V0 = fmaf(wj, __half2float(h.x), V0);
                    V1 = fmaf(wj, __half2float(h.y), V1);
                }
            }
            __syncthreads();   // B1

            if (isv) {
                const float beta_new = betas[i - 1];
                const float mxl = mx2s;
                float S = S_pres, e;
                if (beta_new > mxl) {
                    const float sc = __expf(mxl - beta_new);
                    V0 *= sc; V1 *= sc; S *= sc; e = 1.f;
                } else {
                    e = __expf(beta_new - mxl);
                }
                const unsigned int u = histp[(i - 1) * 152 + vt];
                __half2 h; __builtin_memcpy(&h, &u, 4);
                S += e;
                V0 = fmaf(e, __half2float(h.x), V0);
                V1 = fmaf(e, __half2float(h.y), V1);
                const float inv = 1.f / S;
                const float m0 = V0 * inv, m1 = V1 * inv;
                Mlds[2 * vt] = m0;
                Mlds[2 * vt + 1] = m1;
                M2[vt] = packh2(m0, m1);
            }
        } else {
            if (tid < DH) Mlds[tid] = 0.f;
        }
        __syncthreads();   // B4

        // ---- matvec: kp 0..41 from LDS slab, kp 42..149 streamed from L2 ----
        if (tid < ROWS) {
            float a0 = 0.f, a1 = 0.f;
            const unsigned int* wg = PK2L + KP_LDS * PK_STRIDE + R;
            #pragma unroll
            for (int q = 0; q < 108; q += 2) {
                a0 = dot2f(M2[KP_LDS + q],     wg[q * PK_STRIDE],       a0);
                a1 = dot2f(M2[KP_LDS + q + 1], wg[(q + 1) * PK_STRIDE], a1);
            }
            const unsigned int* wl = wlds + tid;
            #pragma unroll
            for (int q = 0; q < KP_LDS; q += 2) {
                a0 = dot2f(M2[q],     wl[q * WL_STR],       a0);
                a1 = dot2f(M2[q + 1], wl[(q + 1) * WL_STR], a1);
            }
            gmv[tid] = a0 + a1;
        }
        __syncthreads();   // B5

        // ---- gates + per-wave early release (waves 0-1) || prep next softmax (wave 2) ----
        if (wid < 2) {
            float rowv = 0.f;
            if (tid < swk) {
                const float Mi = Mlds[D];
                const float hc0 = gmv[0 * swk + tid] + cb0;
                const float hc1 = gmv[1 * swk + tid] + cb1;
                const float hc2 = gmv[2 * swk + tid] + cb2;
                const float rc = sigmoidf_(gi0 + hc0);
                const float zc = sigmoidf_(gi1 + hc1);
                const float nc = tanh_fast(gi2 + rc * hc2);
                const float Cc = (1.f - zc) * nc + zc * Mi;
                const float ip0 = gmv[3 * swk + tid] + pb0;
                const float ip1 = gmv[4 * swk + tid] + pb1;
                const float ip2 = gmv[5 * swk + tid] + pb2;
                const float rp = sigmoidf_(ip0 + gp0);
                const float zp = sigmoidf_(ip1 + gp1);
                const float np = tanh_fast(ip2 + rp * gp2);
                const float Pp = (1.f - zp) * np + zp * xi;
                rowv = Cc + Pp;
            }
            const float pr = __shfl_xor(rowv, 1);
            const unsigned int pairu32 = packh2(rowv, pr);
            if (tid < swk && !(tid & 1)) {
                __hip_atomic_store(&mb32[(long)i * (MROW * 2) + 38 * k + (tid >> 1)], pairu32,
                                   __ATOMIC_RELAXED, __HIP_MEMORY_SCOPE_AGENT);
            }
            float bv = (tid < swk) ? rowv * wkD : 0.f;
            #pragma unroll
            for (int off = 32; off; off >>= 1) bv += __shfl_xor(bv, off);
            asm volatile("s_waitcnt vmcnt(0)" ::: "memory");
            if (lane == 0) {
                unsigned int bbits;
                __builtin_memcpy(&bbits, &bv, 4);
                const unsigned long long pkt =
                    ((unsigned long long)bbits << 32) | (unsigned int)(i + 1);
                __hip_atomic_store(&mb[(long)i * MROW + 152 + 2 * k + wid], pkt,
                                   __ATOMIC_RELAXED, __HIP_MEMORY_SCOPE_AGENT);
            }
            if (tid < swk) ycol[(long)i * OUTD + D] = rowv;
        } else if (wid == 2 && i + 1 < NB) {
            const int j1 = lane + 64;
            const bool v0 = (lane < i) && (a0p != 0);
            const bool v1 = (j1 < i) && (a1p != 0);
            const float aa0 = v0 ? betas[lane] : -3.0e38f;
            const float aa1 = v1 ? betas[j1]   : -3.0e38f;
            float mx = fmaxf(aa0, aa1);
            #pragma unroll
            for (int off = 32; off; off >>= 1) mx = fmaxf(mx, __shfl_xor(mx, off));
            const float e0 = v0 ? __expf(aa0 - mx) : 0.f;
            const float e1 = v1 ? __expf(aa1 - mx) : 0.f;
            float s = e0 + e1;
            #pragma unroll
            for (int off = 32; off; off >>= 1) s += __shfl_xor(s, off);
            wsm2[lane] = e0;
            wsm2[j1]   = e1;
            if (lane == 0) { mx2s = mx; S_pres = s; }
        }
        __syncthreads();   // B6
    }
}

extern "C" void kernel_launch(void* const* d_in, const int* in_sizes, int n_in,
                              void* d_out, int out_size, void* d_ws, size_t ws_size,
                              hipStream_t stream) {
    (void)in_sizes; (void)n_in; (void)out_size; (void)ws_size;
    const float* features = (const float*)d_in[0];
    const float* fc1_w    = (const float*)d_in[1];
    const float* fc1_b    = (const float*)d_in[2];
    const float* gat_w    = (const float*)d_in[3];
    const float* gc_wih   = (const float*)d_in[5];
    const float* gc_whh   = (const float*)d_in[6];
    const float* gc_bih   = (const float*)d_in[7];
    const float* gc_bhh   = (const float*)d_in[8];
    const float* gp_wih   = (const float*)d_in[9];
    const float* gp_whh   = (const float*)d_in[10];
    const float* gp_bih   = (const float*)d_in[11];
    const float* gp_bhh   = (const float*)d_in[12];
    const int*   adj      = (const int*)d_in[13];
    float* out = (float*)d_out;

    unsigned long long* TB = (unsigned long long*)d_ws;            // 2*64*128*160 u64
    float* GIC = (float*)(TB + 2L * B_ * NB * MROW);               // 8192*900 f32
    float* GHP = GIC + (long)B_ * NB * G3;
    unsigned int* PK2  = (unsigned int*)(GHP + (long)B_ * NB * G3); // 2*150*1800
    unsigned int* APK2 = PK2 + 2 * 150 * PK_STRIDE;                 // 8192*160
    unsigned int* BPKF = APK2 + 8192L * 160;                        // 320*512
    unsigned int* BPKL = BPKF + 320L * 512;                         // 4*960*160
    unsigned int* APK1 = (unsigned int*)GIC;                        // alias

    const int dynlds = (128 * 152 + KP_LDS * WL_STR) * 4;          // 154432 B
    hipFuncSetAttribute(reinterpret_cast<const void*>(scan11),
                        hipFuncAttributeMaxDynamicSharedMemorySize, dynlds);
    hipMemsetAsync(TB, 0, 2L * B_ * NB * MROW * sizeof(unsigned long long), stream);

    copy_feat<<<dim3((B_ * NB * E_) / 1024), 256, 0, stream>>>(features, out);
    pack2<<<dim3((2 * 150 * PK_STRIDE + 255) / 256), 256, 0, stream>>>(gc_whh, gp_wih, PK2);

    pack_af<<<dim3(8192 * 512 / 256), 256, 0, stream>>>(features, APK1);
    pack_bf<<<dim3(320 * 512 / 256), 256, 0, stream>>>(fc1_w, BPKF);
    pack_bw<<<dim3(960 * 160 / 256), 256, 0, stream>>>(gc_wih,           BPKL + 0L * 153600);
    pack_bw<<<dim3(960 * 160 / 256), 256, 0, stream>>>(gp_whh,           BPKL + 1L * 153600);
    pack_bw<<<dim3(960 * 160 / 256), 256, 0, stream>>>(gc_wih + G3 * DH, BPKL + 2L * 153600);
    pack_bw<<<dim3(960 * 160 / 256), 256, 0, stream>>>(gp_whh + G3 * DH, BPKL + 3L * 153600);

    // H0 = relu(features @ fc1_w + b) -> out cols [0,300)
    gemm_h16<1><<<dim3(5, 64), 256, 0, stream>>>(APK1, 512, BPKF, 512, fc1_b, out, OUTD, DH, 512);

    for (int l = 0; l < 2; ++l) {
        pack_ah<<<dim3(8192 * 160 / 256), 256, 0, stream>>>(out + l * DH, APK2);
        gemm_h16<0><<<dim3(15, 64), 256, 0, stream>>>(
            APK2, 160, BPKL + (2L * l) * 153600, 160, gc_bih + l * G3, GIC, G3, G3, 160);
        gemm_h16<0><<<dim3(15, 64), 256, 0, stream>>>(
            APK2, 160, BPKL + (2L * l + 1) * 153600, 160, gp_bhh + l * G3, GHP, G3, G3, 160);
        scan11<<<dim3(SLICES * B_), 512, dynlds, stream>>>(
            out, GIC, GHP, PK2 + (long)l * 150 * PK_STRIDE,
            gc_bhh + l * G3, gp_bih + l * G3, adj,
            gat_w + l * 2 * DH + DH,
            TB + (long)l * B_ * NB * MROW, l);
    }
}

// Round 13
// 1445.173 us; speedup vs baseline: 1.4613x; 1.4613x over previous
//
#include <hip/hip_runtime.h>
#include <hip/hip_fp16.h>

#define B_   64
#define NB   128
#define E_   1024
#define DH   300
#define G3   900
#define OUTD 1924
#define SLICES 4
#define PK_STRIDE 1800
#define MROW 160   // u64/row: u32 data words [0..149], tag u64s [152..159]

typedef _Float16 h2raw __attribute__((ext_vector_type(2)));

__device__ __forceinline__ float dot2f(unsigned int m2, unsigned int w, float acc) {
    h2raw a, b;
    __builtin_memcpy(&a, &m2, 4);
    __builtin_memcpy(&b, &w, 4);
    return __builtin_amdgcn_fdot2(a, b, acc, false);
}

__device__ __forceinline__ unsigned int packh2(float x, float y) {
    __half2 h;
    h.x = __float2half_rn(x);
    h.y = __float2half_rn(y);
    unsigned int u;
    __builtin_memcpy(&u, &h, 4);
    return u;
}

__device__ __forceinline__ float sigmoidf_(float x) { return 1.f / (1.f + __expf(-x)); }
__device__ __forceinline__ float tanh_fast(float x) { return 1.f - 2.f / (__expf(2.f * x) + 1.f); }

// ---------------- copy features into output tail ----------------
__global__ __launch_bounds__(256)
void copy_feat(const float* __restrict__ f, float* __restrict__ out) {
    const long id = (long)blockIdx.x * 256 + threadIdx.x;
    const long r = id >> 8;
    const int  c = (int)(id & 255);
    const float4 v = ((const float4*)(f + r * E_))[c];
    ((float4*)(out + r * OUTD + 3 * DH))[c] = v;
}

// ---------------- pack recurrent weights -> PK2[l][kp(150)][R(1800)] f16-pairs (kp-major) ----------------
__global__ __launch_bounds__(256)
void pack2(const float* __restrict__ gc_whh, const float* __restrict__ gp_wih,
           unsigned int* __restrict__ dst) {
    const int id = blockIdx.x * 256 + threadIdx.x;
    if (id >= 2 * 150 * PK_STRIDE) return;
    const int l   = id / (150 * PK_STRIDE);
    const int rem = id % (150 * PK_STRIDE);
    const int kp  = rem / PK_STRIDE;
    const int R   = rem % PK_STRIDE;
    const int mat = R / G3;
    const int o   = R % G3;
    const float* W = (mat ? gp_wih : gc_whh) + (long)l * G3 * DH;
    const float2 v = *(const float2*)(W + (long)o * DH + 2 * kp);
    dst[id] = packh2(v.x, v.y);
}

// ---------------- GEMM input packing to f16 pairs ----------------
__global__ __launch_bounds__(256)
void pack_af(const float* __restrict__ src, unsigned int* __restrict__ dst) {
    const long id = (long)blockIdx.x * 256 + threadIdx.x;   // 8192*512
    const long r = id >> 9;
    const int kp = (int)(id & 511);
    const float2 v = *(const float2*)(src + r * E_ + 2 * kp);
    dst[id] = packh2(v.x, v.y);
}

__global__ __launch_bounds__(256)
void pack_ah(const float* __restrict__ src, unsigned int* __restrict__ dst) {
    const long id = (long)blockIdx.x * 256 + threadIdx.x;   // 8192*160
    const long r = id / 160;
    const int kp = (int)(id % 160);
    unsigned int u = 0u;
    if (kp < 150) {
        const float2 v = *(const float2*)(src + r * OUTD + 2 * kp);
        u = packh2(v.x, v.y);
    }
    dst[id] = u;
}

__global__ __launch_bounds__(256)
void pack_bf(const float* __restrict__ W, unsigned int* __restrict__ dst) {
    const int id = blockIdx.x * 256 + threadIdx.x;          // 320*512
    const int n = id >> 9;
    const int kp = id & 511;
    unsigned int u = 0u;
    if (n < DH) u = packh2(W[(2 * kp) * DH + n], W[(2 * kp + 1) * DH + n]);
    dst[id] = u;
}

__global__ __launch_bounds__(256)
void pack_bw(const float* __restrict__ W, unsigned int* __restrict__ dst) {
    const int id = blockIdx.x * 256 + threadIdx.x;          // 960*160
    const int n = id / 160;
    const int kp = id % 160;
    unsigned int u = 0u;
    if (n < G3 && kp < 150) {
        const float2 v = *(const float2*)(W + (long)n * DH + 2 * kp);
        u = packh2(v.x, v.y);
    }
    dst[id] = u;
}

// ---------------- f16-dot2 GEMM ----------------
template<int RELU>
__global__ __launch_bounds__(256)
void gemm_h16(const unsigned int* __restrict__ APK, int ldap,
              const unsigned int* __restrict__ BPK, int ldbp,
              const float* __restrict__ bias,
              float* __restrict__ C, int ldc,
              int N, int KP)
{
    __shared__ __align__(16) unsigned int As[16][132];
    __shared__ __align__(16) unsigned int Bs[16][68];
    const int tid = threadIdx.x;
    const int m0 = blockIdx.y * 128;
    const int n0 = blockIdx.x * 64;
    const int tx = tid & 15, ty = tid >> 4;
    const int am = tid >> 1, ak8 = (tid & 1) * 8;
    const int bn = tid >> 2, bk4 = (tid & 3) * 4;

    float acc[8][4] = {{0.f}};
    const unsigned int* ap = APK + (long)(m0 + am) * ldap + ak8;
    const unsigned int* bp = BPK + (long)(n0 + bn) * ldbp + bk4;

    for (int kp0 = 0; kp0 < KP; kp0 += 16) {
        const uint4 a0 = *(const uint4*)(ap + kp0);
        const uint4 a1 = *(const uint4*)(ap + kp0 + 4);
        const uint4 bq = *(const uint4*)(bp + kp0);
        As[ak8 + 0][am] = a0.x; As[ak8 + 1][am] = a0.y;
        As[ak8 + 2][am] = a0.z; As[ak8 + 3][am] = a0.w;
        As[ak8 + 4][am] = a1.x; As[ak8 + 5][am] = a1.y;
        As[ak8 + 6][am] = a1.z; As[ak8 + 7][am] = a1.w;
        Bs[bk4 + 0][bn] = bq.x; Bs[bk4 + 1][bn] = bq.y;
        Bs[bk4 + 2][bn] = bq.z; Bs[bk4 + 3][bn] = bq.w;
        __syncthreads();
        #pragma unroll
        for (int kp = 0; kp < 16; ++kp) {
            const uint4 aA = *(const uint4*)&As[kp][ty * 8];
            const uint4 aB = *(const uint4*)&As[kp][ty * 8 + 4];
            const uint4 bb = *(const uint4*)&Bs[kp][tx * 4];
            const unsigned int av[8] = {aA.x, aA.y, aA.z, aA.w, aB.x, aB.y, aB.z, aB.w};
            const unsigned int bv[4] = {bb.x, bb.y, bb.z, bb.w};
            #pragma unroll
            for (int ii = 0; ii < 8; ++ii)
                #pragma unroll
                for (int jj = 0; jj < 4; ++jj)
                    acc[ii][jj] = dot2f(av[ii], bv[jj], acc[ii][jj]);
        }
        __syncthreads();
    }

    const int gn0 = n0 + tx * 4;
    #pragma unroll
    for (int ii = 0; ii < 8; ++ii) {
        const int gm = m0 + ty * 8 + ii;
        float* cp = C + (long)gm * ldc + gn0;
        if (gn0 + 3 < N) {
            const float4 bb = *(const float4*)&bias[gn0];
            float4 o;
            o.x = acc[ii][0] + bb.x; o.y = acc[ii][1] + bb.y;
            o.z = acc[ii][2] + bb.z; o.w = acc[ii][3] + bb.w;
            if (RELU) { o.x = fmaxf(o.x, 0.f); o.y = fmaxf(o.y, 0.f); o.z = fmaxf(o.z, 0.f); o.w = fmaxf(o.w, 0.f); }
            *(float4*)cp = o;
        } else if (gn0 < N) {
            for (int jj = 0; jj < 4; ++jj) {
                const int gn = gn0 + jj;
                if (gn < N) {
                    float v = acc[ii][jj] + bias[gn];
                    if (RELU) v = fmaxf(v, 0.f);
                    cp[jj] = v;
                }
            }
        }
    }
}

// ---------------- DAG scan v13: v12 with ROWS-coverage fix (912 = 2x456 matvec threads) ----------------
__global__ __launch_bounds__(1024, 1)
void scan13(float* __restrict__ out,
            const float* __restrict__ GIC,
            const float* __restrict__ GHP,
            const unsigned int* __restrict__ PK2L,  // kp-major [150][1800]
            const float* __restrict__ cbhh,
            const float* __restrict__ pbih,
            const int* __restrict__ adj,
            const float* __restrict__ wk,
            unsigned long long* __restrict__ TBL,
            int l)
{
    extern __shared__ unsigned int histp[];   // [128][152] f16-pairs
    __shared__ float wsm2[NB];
    __shared__ float betas[NB];
    __shared__ float Mlds[DH];
    __shared__ __align__(16) unsigned int M2[152];
    __shared__ float gmv2[2 * 456];
    __shared__ float mx2s, S_pres;

    const int tid = threadIdx.x;
    const int lane = tid & 63;
    const int wid = tid >> 6;
    const int b = blockIdx.x & 63;
    const int k = blockIdx.x >> 6;
    const int swk = (k == 3) ? 72 : 76;

    float* outb = out + (long)b * NB * OUTD;
    const float* xcol = outb + l * DH;
    float* ycol = outb + (l + 1) * DH;
    const float* gicb = GIC + (long)b * NB * G3;
    const float* ghpb = GHP + (long)b * NB * G3;
    const int* adjb = adj + b * NB * NB;
    unsigned long long* mb = TBL + (long)b * NB * MROW;
    unsigned int* mb32 = (unsigned int*)mb;

    if (tid < 152) M2[tid] = 0u;

    const int D = 76 * k + ((tid < swk) ? tid : 0);
    const float cb0 = cbhh[D], cb1 = cbhh[DH + D], cb2 = cbhh[2 * DH + D];
    const float pb0 = pbih[D], pb1 = pbih[DH + D], pb2 = pbih[2 * DH + D];
    const float wkD = wk[D];

    const int ROWS = 6 * swk;          // 456 / 432
    // matvec thread: row mr (0..455), K-half mh (0..1); 912 threads
    const int mvt = (tid < 912) ? tid : 0;
    const int mr = mvt % 456;
    const int mh = mvt / 456;
    int R;
    {
        const int t = (mr < ROWS) ? mr : 0;
        const int d = t % swk;
        const int r = t / swk;
        R = (r / 3) * G3 + (r % 3) * DH + 76 * k + d;
    }
    // this thread's 76-pair K-half of the weight row (kp = 76*mh + j; zero past 149)
    unsigned int w[76];
    #pragma unroll
    for (int j = 0; j < 76; ++j) {
        const int kp = 76 * mh + j;
        w[j] = (kp < 150) ? PK2L[kp * PK_STRIDE + R] : 0u;
    }

    __syncthreads();

    const bool isv = (tid >= 256) && (tid < 406);
    const int vt = tid - 256;

    for (int i = 0; i < NB; ++i) {
        // ---- top-of-step prefetches ----
        float gi0 = 0, gi1 = 0, gi2 = 0, gp0 = 0, gp1 = 0, gp2 = 0, xi = 0;
        if (tid < swk) {
            const float* gic = gicb + (long)i * G3;
            const float* ghp = ghpb + (long)i * G3;
            gi0 = gic[D]; gi1 = gic[DH + D]; gi2 = gic[2 * DH + D];
            gp0 = ghp[D]; gp1 = ghp[DH + D]; gp2 = ghp[2 * DH + D];
            xi = xcol[(long)i * OUTD + D];
        }
        int a0p = 0, a1p = 0;
        if (wid == 2 && i + 1 < NB) {
            a0p = adjb[(i + 1) * NB + lane];
            a1p = adjb[(i + 1) * NB + 64 + lane];
        }

        if (i > 0) {
            float V0 = 0.f, V1 = 0.f;
            if (wid == 0) {
                // ---- poll 8 self-describing tag words ----
                const unsigned long long* trow = mb + (long)(i - 1) * MROW;
                const unsigned int tag = (unsigned int)i;
                const bool act = (lane < 8);
                unsigned long long tv = 0;
                while (true) {
                    if (act && (unsigned int)tv != tag)
                        tv = __hip_atomic_load(&trow[152 + lane],
                                               __ATOMIC_RELAXED, __HIP_MEMORY_SCOPE_AGENT);
                    if (__all(!act || (unsigned int)tv == tag)) break;
                }
                // issue data loads immediately (latency overlaps beta reduce)
                unsigned long long d0 = 0, d1 = 0;
                if (lane < 38) {
                    d0 = __hip_atomic_load(&trow[2 * lane],
                                           __ATOMIC_RELAXED, __HIP_MEMORY_SCOPE_AGENT);
                    d1 = __hip_atomic_load(&trow[2 * lane + 1],
                                           __ATOMIC_RELAXED, __HIP_MEMORY_SCOPE_AGENT);
                }
                float bp = 0.f;
                if (act) {
                    const unsigned int hb = (unsigned int)(tv >> 32);
                    __builtin_memcpy(&bp, &hb, 4);
                }
                bp += __shfl_xor(bp, 1);
                bp += __shfl_xor(bp, 2);
                bp += __shfl_xor(bp, 4);
                if (lane == 0) betas[i - 1] = __shfl(bp, 0);

                if (lane < 38) {
                    uint4 q;
                    q.x = (unsigned int)d0; q.y = (unsigned int)(d0 >> 32);
                    q.z = (unsigned int)d1; q.w = (unsigned int)(d1 >> 32);
                    *(uint4*)&histp[(i - 1) * 152 + 4 * lane] = q;
                }
            } else if (isv) {
                // ---- V-loop over j <= i-2 with precomputed unnormalized weights ----
                #pragma unroll 4
                for (int j = 0; j + 1 < i; ++j) {
                    const float wj = wsm2[j];
                    const unsigned int u = histp[j * 152 + vt];
                    __half2 h; __builtin_memcpy(&h, &u, 4);
                    V0 = fmaf(wj, __half2float(h.x), V0);
                    V1 = fmaf(wj, __half2float(h.y), V1);
                }
            }
            __syncthreads();   // B1

            if (isv) {
                const float beta_new = betas[i - 1];
                const float mxl = mx2s;
                float S = S_pres, e;
                if (beta_new > mxl) {
                    const float sc = __expf(mxl - beta_new);
                    V0 *= sc; V1 *= sc; S *= sc; e = 1.f;
                } else {
                    e = __expf(beta_new - mxl);
                }
                const unsigned int u = histp[(i - 1) * 152 + vt];
                __half2 h; __builtin_memcpy(&h, &u, 4);
                S += e;
                V0 = fmaf(e, __half2float(h.x), V0);
                V1 = fmaf(e, __half2float(h.y), V1);
                const float inv = 1.f / S;
                const float m0 = V0 * inv, m1 = V1 * inv;
                Mlds[2 * vt] = m0;
                Mlds[2 * vt + 1] = m1;
                M2[vt] = packh2(m0, m1);
            }
        } else {
            if (tid < DH) Mlds[tid] = 0.f;
        }
        __syncthreads();   // B4

        // ---- matvec: 912 threads, each one (row, K-half); 19 uint4 of M2 + private w ----
        if (tid < 912) {
            float a0 = 0.f, a1 = 0.f;
            #pragma unroll
            for (int q = 0; q < 19; ++q) {
                const uint4 m4 = *(const uint4*)&M2[76 * mh + 4 * q];
                a0 = dot2f(m4.x, w[4 * q + 0], a0);
                a1 = dot2f(m4.y, w[4 * q + 1], a1);
                a0 = dot2f(m4.z, w[4 * q + 2], a0);
                a1 = dot2f(m4.w, w[4 * q + 3], a1);
            }
            gmv2[456 * mh + mr] = a0 + a1;
        }
        __syncthreads();   // B5

        // ---- gates + per-wave early release (waves 0-1) || prep next softmax (wave 2) ----
        if (wid < 2) {
            float rowv = 0.f;
            if (tid < swk) {
                const float Mi = Mlds[D];
                const float hc0 = gmv2[0 * swk + tid] + gmv2[456 + 0 * swk + tid] + cb0;
                const float hc1 = gmv2[1 * swk + tid] + gmv2[456 + 1 * swk + tid] + cb1;
                const float hc2 = gmv2[2 * swk + tid] + gmv2[456 + 2 * swk + tid] + cb2;
                const float rc = sigmoidf_(gi0 + hc0);
                const float zc = sigmoidf_(gi1 + hc1);
                const float nc = tanh_fast(gi2 + rc * hc2);
                const float Cc = (1.f - zc) * nc + zc * Mi;
                const float ip0 = gmv2[3 * swk + tid] + gmv2[456 + 3 * swk + tid] + pb0;
                const float ip1 = gmv2[4 * swk + tid] + gmv2[456 + 4 * swk + tid] + pb1;
                const float ip2 = gmv2[5 * swk + tid] + gmv2[456 + 5 * swk + tid] + pb2;
                const float rp = sigmoidf_(ip0 + gp0);
                const float zp = sigmoidf_(ip1 + gp1);
                const float np = tanh_fast(ip2 + rp * gp2);
                const float Pp = (1.f - zp) * np + zp * xi;
                rowv = Cc + Pp;
            }
            const float pr = __shfl_xor(rowv, 1);
            const unsigned int pairu32 = packh2(rowv, pr);
            if (tid < swk && !(tid & 1)) {
                __hip_atomic_store(&mb32[(long)i * (MROW * 2) + 38 * k + (tid >> 1)], pairu32,
                                   __ATOMIC_RELAXED, __HIP_MEMORY_SCOPE_AGENT);
            }
            float bv = (tid < swk) ? rowv * wkD : 0.f;
            #pragma unroll
            for (int off = 32; off; off >>= 1) bv += __shfl_xor(bv, off);
            asm volatile("s_waitcnt vmcnt(0)" ::: "memory");
            if (lane == 0) {
                unsigned int bbits;
                __builtin_memcpy(&bbits, &bv, 4);
                const unsigned long long pkt =
                    ((unsigned long long)bbits << 32) | (unsigned int)(i + 1);
                __hip_atomic_store(&mb[(long)i * MROW + 152 + 2 * k + wid], pkt,
                                   __ATOMIC_RELAXED, __HIP_MEMORY_SCOPE_AGENT);
            }
            if (tid < swk) ycol[(long)i * OUTD + D] = rowv;
        } else if (wid == 2 && i + 1 < NB) {
            const int j1 = lane + 64;
            const bool v0 = (lane < i) && (a0p != 0);
            const bool v1 = (j1 < i) && (a1p != 0);
            const float aa0 = v0 ? betas[lane] : -3.0e38f;
            const float aa1 = v1 ? betas[j1]   : -3.0e38f;
            float mx = fmaxf(aa0, aa1);
            #pragma unroll
            for (int off = 32; off; off >>= 1) mx = fmaxf(mx, __shfl_xor(mx, off));
            const float e0 = v0 ? __expf(aa0 - mx) : 0.f;
            const float e1 = v1 ? __expf(aa1 - mx) : 0.f;
            float s = e0 + e1;
            #pragma unroll
            for (int off = 32; off; off >>= 1) s += __shfl_xor(s, off);
            wsm2[lane] = e0;
            wsm2[j1]   = e1;
            if (lane == 0) { mx2s = mx; S_pres = s; }
        }
        __syncthreads();   // B6
    }
}

extern "C" void kernel_launch(void* const* d_in, const int* in_sizes, int n_in,
                              void* d_out, int out_size, void* d_ws, size_t ws_size,
                              hipStream_t stream) {
    (void)in_sizes; (void)n_in; (void)out_size; (void)ws_size;
    const float* features = (const float*)d_in[0];
    const float* fc1_w    = (const float*)d_in[1];
    const float* fc1_b    = (const float*)d_in[2];
    const float* gat_w    = (const float*)d_in[3];
    const float* gc_wih   = (const float*)d_in[5];
    const float* gc_whh   = (const float*)d_in[6];
    const float* gc_bih   = (const float*)d_in[7];
    const float* gc_bhh   = (const float*)d_in[8];
    const float* gp_wih   = (const float*)d_in[9];
    const float* gp_whh   = (const float*)d_in[10];
    const float* gp_bih   = (const float*)d_in[11];
    const float* gp_bhh   = (const float*)d_in[12];
    const int*   adj      = (const int*)d_in[13];
    float* out = (float*)d_out;

    unsigned long long* TB = (unsigned long long*)d_ws;            // 2*64*128*160 u64
    float* GIC = (float*)(TB + 2L * B_ * NB * MROW);               // 8192*900 f32
    float* GHP = GIC + (long)B_ * NB * G3;
    unsigned int* PK2  = (unsigned int*)(GHP + (long)B_ * NB * G3); // 2*150*1800
    unsigned int* APK2 = PK2 + 2 * 150 * PK_STRIDE;                 // 8192*160
    unsigned int* BPKF = APK2 + 8192L * 160;                        // 320*512
    unsigned int* BPKL = BPKF + 320L * 512;                         // 4*960*160
    unsigned int* APK1 = (unsigned int*)GIC;                        // alias

    hipFuncSetAttribute(reinterpret_cast<const void*>(scan13),
                        hipFuncAttributeMaxDynamicSharedMemorySize, 80000);
    hipMemsetAsync(TB, 0, 2L * B_ * NB * MROW * sizeof(unsigned long long), stream);

    copy_feat<<<dim3((B_ * NB * E_) / 1024), 256, 0, stream>>>(features, out);
    pack2<<<dim3((2 * 150 * PK_STRIDE + 255) / 256), 256, 0, stream>>>(gc_whh, gp_wih, PK2);

    pack_af<<<dim3(8192 * 512 / 256), 256, 0, stream>>>(features, APK1);
    pack_bf<<<dim3(320 * 512 / 256), 256, 0, stream>>>(fc1_w, BPKF);
    pack_bw<<<dim3(960 * 160 / 256), 256, 0, stream>>>(gc_wih,           BPKL + 0L * 153600);
    pack_bw<<<dim3(960 * 160 / 256), 256, 0, stream>>>(gp_whh,           BPKL + 1L * 153600);
    pack_bw<<<dim3(960 * 160 / 256), 256, 0, stream>>>(gc_wih + G3 * DH, BPKL + 2L * 153600);
    pack_bw<<<dim3(960 * 160 / 256), 256, 0, stream>>>(gp_whh + G3 * DH, BPKL + 3L * 153600);

    // H0 = relu(features @ fc1_w + b) -> out cols [0,300)
    gemm_h16<1><<<dim3(5, 64), 256, 0, stream>>>(APK1, 512, BPKF, 512, fc1_b, out, OUTD, DH, 512);

    for (int l = 0; l < 2; ++l) {
        pack_ah<<<dim3(8192 * 160 / 256), 256, 0, stream>>>(out + l * DH, APK2);
        gemm_h16<0><<<dim3(15, 64), 256, 0, stream>>>(
            APK2, 160, BPKL + (2L * l) * 153600, 160, gc_bih + l * G3, GIC, G3, G3, 160);
        gemm_h16<0><<<dim3(15, 64), 256, 0, stream>>>(
            APK2, 160, BPKL + (2L * l + 1) * 153600, 160, gp_bhh + l * G3, GHP, G3, G3, 160);
        scan13<<<dim3(SLICES * B_), 1024, 77824, stream>>>(
            out, GIC, GHP, PK2 + (long)l * 150 * PK_STRIDE,
            gc_bhh + l * G3, gp_bih + l * G3, adj,
            gat_w + l * 2 * DH + DH,
            TB + (long)l * B_ * NB * MROW, l);
    }
}

// Round 14
// 1173.534 us; speedup vs baseline: 1.7996x; 1.2315x over previous
//
#include <hip/hip_runtime.h>
#include <hip/hip_fp16.h>

#define B_   64
#define NB   128
#define E_   1024
#define DH   300
#define G3   900
#define G6   1800
#define OUTD 1924
#define SLICES 4
#define PK_STRIDE 1800
#define MROW 160   // u64/row: u32 data words [0..149], tag u64s [152..159]
#define BROWS 1856 // padded B rows for fused layer GEMM

typedef _Float16 h2raw __attribute__((ext_vector_type(2)));

__device__ __forceinline__ float dot2f(unsigned int m2, unsigned int w, float acc) {
    h2raw a, b;
    __builtin_memcpy(&a, &m2, 4);
    __builtin_memcpy(&b, &w, 4);
    return __builtin_amdgcn_fdot2(a, b, acc, false);
}

__device__ __forceinline__ unsigned int packh2(float x, float y) {
    __half2 h;
    h.x = __float2half_rn(x);
    h.y = __float2half_rn(y);
    unsigned int u;
    __builtin_memcpy(&u, &h, 4);
    return u;
}

__device__ __forceinline__ float sigmoidf_(float x) { return 1.f / (1.f + __expf(-x)); }
__device__ __forceinline__ float tanh_fast(float x) { return 1.f - 2.f / (__expf(2.f * x) + 1.f); }

// ---------------- copy features into output tail ----------------
__global__ __launch_bounds__(256)
void copy_feat(const float* __restrict__ f, float* __restrict__ out) {
    const long id = (long)blockIdx.x * 256 + threadIdx.x;
    const long r = id >> 8;
    const int  c = (int)(id & 255);
    const float4 v = ((const float4*)(f + r * E_))[c];
    ((float4*)(out + r * OUTD + 3 * DH))[c] = v;
}

// ---------------- pack recurrent weights -> PK2[l][kp(150)][R(1800)] f16-pairs (kp-major) ----------------
__global__ __launch_bounds__(256)
void pack2(const float* __restrict__ gc_whh, const float* __restrict__ gp_wih,
           unsigned int* __restrict__ dst) {
    const int id = blockIdx.x * 256 + threadIdx.x;
    if (id >= 2 * 150 * PK_STRIDE) return;
    const int l   = id / (150 * PK_STRIDE);
    const int rem = id % (150 * PK_STRIDE);
    const int kp  = rem / PK_STRIDE;
    const int R   = rem % PK_STRIDE;
    const int mat = R / G3;
    const int o   = R % G3;
    const float* W = (mat ? gp_wih : gc_whh) + (long)l * G3 * DH;
    const float2 v = *(const float2*)(W + (long)o * DH + 2 * kp);
    dst[id] = packh2(v.x, v.y);
}

// ---------------- GEMM input packing ----------------
__global__ __launch_bounds__(256)
void pack_af(const float* __restrict__ src, unsigned int* __restrict__ dst) {
    const long id = (long)blockIdx.x * 256 + threadIdx.x;   // 8192*512
    const long r = id >> 9;
    const int kp = (int)(id & 511);
    const float2 v = *(const float2*)(src + r * E_ + 2 * kp);
    dst[id] = packh2(v.x, v.y);
}

__global__ __launch_bounds__(256)
void pack_bf(const float* __restrict__ W, unsigned int* __restrict__ dst) {
    const int id = blockIdx.x * 256 + threadIdx.x;          // 320*512
    const int n = id >> 9;
    const int kp = id & 511;
    unsigned int u = 0u;
    if (n < DH) u = packh2(W[(2 * kp) * DH + n], W[(2 * kp + 1) * DH + n]);
    dst[id] = u;
}

// fused layer-B pack: rows 0..899 = cwih, 900..1799 = pwhh, rest zero -> [BROWS][160]
__global__ __launch_bounds__(256)
void pack_bw2(const float* __restrict__ Wc, const float* __restrict__ Wp,
              unsigned int* __restrict__ dst) {
    const int id = blockIdx.x * 256 + threadIdx.x;
    if (id >= 2 * BROWS * 160) return;
    const int l   = id / (BROWS * 160);
    const int rem = id % (BROWS * 160);
    const int n   = rem / 160;
    const int kp  = rem % 160;
    unsigned int u = 0u;
    if (n < G6 && kp < 150) {
        const float* W = (n < G3 ? Wc : Wp) + (long)l * G3 * DH;
        const int o = (n < G3) ? n : n - G3;
        const float2 v = *(const float2*)(W + (long)o * DH + 2 * kp);
        u = packh2(v.x, v.y);
    }
    dst[id] = u;
}

// ---------------- f16-dot2 GEMM (optional packed-f16 secondary output, split bias) ----------------
template<int RELU, int PACKOUT>
__global__ __launch_bounds__(256)
void gemm_h16(const unsigned int* __restrict__ APK, int ldap,
              const unsigned int* __restrict__ BPK, int ldbp,
              const float* __restrict__ bias1, const float* __restrict__ bias2, int bsplit,
              float* __restrict__ C, int ldc,
              unsigned int* __restrict__ CPK, int ldcp,
              int N, int KP)
{
    __shared__ __align__(16) unsigned int As[16][132];
    __shared__ __align__(16) unsigned int Bs[16][68];
    const int tid = threadIdx.x;
    const int m0 = blockIdx.y * 128;
    const int n0 = blockIdx.x * 64;
    const int tx = tid & 15, ty = tid >> 4;
    const int am = tid >> 1, ak8 = (tid & 1) * 8;
    const int bn = tid >> 2, bk4 = (tid & 3) * 4;

    float acc[8][4] = {{0.f}};
    const unsigned int* ap = APK + (long)(m0 + am) * ldap + ak8;
    const unsigned int* bp = BPK + (long)(n0 + bn) * ldbp + bk4;

    for (int kp0 = 0; kp0 < KP; kp0 += 16) {
        const uint4 a0 = *(const uint4*)(ap + kp0);
        const uint4 a1 = *(const uint4*)(ap + kp0 + 4);
        const uint4 bq = *(const uint4*)(bp + kp0);
        As[ak8 + 0][am] = a0.x; As[ak8 + 1][am] = a0.y;
        As[ak8 + 2][am] = a0.z; As[ak8 + 3][am] = a0.w;
        As[ak8 + 4][am] = a1.x; As[ak8 + 5][am] = a1.y;
        As[ak8 + 6][am] = a1.z; As[ak8 + 7][am] = a1.w;
        Bs[bk4 + 0][bn] = bq.x; Bs[bk4 + 1][bn] = bq.y;
        Bs[bk4 + 2][bn] = bq.z; Bs[bk4 + 3][bn] = bq.w;
        __syncthreads();
        #pragma unroll
        for (int kp = 0; kp < 16; ++kp) {
            const uint4 aA = *(const uint4*)&As[kp][ty * 8];
            const uint4 aB = *(const uint4*)&As[kp][ty * 8 + 4];
            const uint4 bb = *(const uint4*)&Bs[kp][tx * 4];
            const unsigned int av[8] = {aA.x, aA.y, aA.z, aA.w, aB.x, aB.y, aB.z, aB.w};
            const unsigned int bv[4] = {bb.x, bb.y, bb.z, bb.w};
            #pragma unroll
            for (int ii = 0; ii < 8; ++ii)
                #pragma unroll
                for (int jj = 0; jj < 4; ++jj)
                    acc[ii][jj] = dot2f(av[ii], bv[jj], acc[ii][jj]);
        }
        __syncthreads();
    }

    const int gn0 = n0 + tx * 4;
    #pragma unroll
    for (int ii = 0; ii < 8; ++ii) {
        const int gm = m0 + ty * 8 + ii;
        float* cp = C + (long)gm * ldc + gn0;
        if (gn0 + 3 < N) {
            const float* bb4 = (gn0 < bsplit) ? bias1 + gn0 : bias2 + (gn0 - bsplit);
            const float4 bb = *(const float4*)bb4;
            float4 o;
            o.x = acc[ii][0] + bb.x; o.y = acc[ii][1] + bb.y;
            o.z = acc[ii][2] + bb.z; o.w = acc[ii][3] + bb.w;
            if (RELU) { o.x = fmaxf(o.x, 0.f); o.y = fmaxf(o.y, 0.f); o.z = fmaxf(o.z, 0.f); o.w = fmaxf(o.w, 0.f); }
            *(float4*)cp = o;
            if (PACKOUT) {
                unsigned int* pk = CPK + (long)gm * ldcp + (gn0 >> 1);
                pk[0] = packh2(o.x, o.y);
                pk[1] = packh2(o.z, o.w);
            }
        } else if (gn0 < N) {
            for (int jj = 0; jj < 4; ++jj) {
                const int gn = gn0 + jj;
                if (gn < N) {
                    float v = acc[ii][jj] + ((gn < bsplit) ? bias1[gn] : bias2[gn - bsplit]);
                    if (RELU) v = fmaxf(v, 0.f);
                    cp[jj] = v;
                }
            }
        }
    }
}

// ---------------- DAG scan v14 == scan9 (proven 464us), fused GG buffer + packed-A side-write ----------------
__global__ __launch_bounds__(512, 2)
void scan14(float* __restrict__ out,
            const float* __restrict__ GG,          // [8192][1800]: cols 0-899 gi_c, 900-1799 gh_p
            const unsigned int* __restrict__ PK2L, // kp-major [150][1800]
            const float* __restrict__ cbhh,
            const float* __restrict__ pbih,
            const int* __restrict__ adj,
            const float* __restrict__ wk,
            unsigned long long* __restrict__ TBL,
            unsigned int* __restrict__ APKN,       // packed A for next layer (l==0), else unused
            int l)
{
    extern __shared__ unsigned int histp[];   // [128][152] f16-pairs
    __shared__ float wsm2[NB];
    __shared__ float betas[NB];
    __shared__ float Mlds[DH];
    __shared__ __align__(16) unsigned int M2[152];
    __shared__ float gmv[456];
    __shared__ float mx2s, S_pres;

    const int tid = threadIdx.x;
    const int lane = tid & 63;
    const int wid = tid >> 6;
    const int b = blockIdx.x & 63;
    const int k = blockIdx.x >> 6;
    const int swk = (k == 3) ? 72 : 76;

    float* outb = out + (long)b * NB * OUTD;
    const float* xcol = outb + l * DH;
    float* ycol = outb + (l + 1) * DH;
    const float* ggb = GG + (long)b * NB * G6;
    const int* adjb = adj + b * NB * NB;
    unsigned long long* mb = TBL + (long)b * NB * MROW;
    unsigned int* mb32 = (unsigned int*)mb;

    if (tid < 152) M2[tid] = 0u;

    const int D = 76 * k + ((tid < swk) ? tid : 0);
    const float cb0 = cbhh[D], cb1 = cbhh[DH + D], cb2 = cbhh[2 * DH + D];
    const float pb0 = pbih[D], pb1 = pbih[DH + D], pb2 = pbih[2 * DH + D];
    const float wkD = wk[D];

    const int ROWS = 6 * swk;
    int R;
    {
        const int t = (tid < ROWS) ? tid : 0;
        const int d = t % swk;
        const int r = t / swk;
        R = (r / 3) * G3 + (r % 3) * DH + 76 * k + d;
    }
    unsigned int w[152];
    #pragma unroll
    for (int j = 0; j < 150; ++j) w[j] = PK2L[j * PK_STRIDE + R];
    w[150] = 0u; w[151] = 0u;

    __syncthreads();

    const bool isv = (tid >= 256) && (tid < 406);
    const int vt = tid - 256;

    for (int i = 0; i < NB; ++i) {
        // ---- top-of-step prefetches ----
        float gi0 = 0, gi1 = 0, gi2 = 0, gp0 = 0, gp1 = 0, gp2 = 0, xi = 0;
        if (tid < swk) {
            const float* gic = ggb + (long)i * G6;
            gi0 = gic[D]; gi1 = gic[DH + D]; gi2 = gic[2 * DH + D];
            gp0 = gic[G3 + D]; gp1 = gic[G3 + DH + D]; gp2 = gic[G3 + 2 * DH + D];
            xi = xcol[(long)i * OUTD + D];
        }
        int a0p = 0, a1p = 0;
        if (wid == 2 && i + 1 < NB) {
            a0p = adjb[(i + 1) * NB + lane];
            a1p = adjb[(i + 1) * NB + 64 + lane];
        }

        if (i > 0) {
            float V0 = 0.f, V1 = 0.f;
            if (wid == 0) {
                // ---- poll 8 self-describing tag words ----
                const unsigned long long* trow = mb + (long)(i - 1) * MROW;
                const unsigned int tag = (unsigned int)i;
                const bool act = (lane < 8);
                unsigned long long tv = 0;
                while (true) {
                    if (act && (unsigned int)tv != tag)
                        tv = __hip_atomic_load(&trow[152 + lane],
                                               __ATOMIC_RELAXED, __HIP_MEMORY_SCOPE_AGENT);
                    if (__all(!act || (unsigned int)tv == tag)) break;
                }
                unsigned long long d0 = 0, d1 = 0;
                if (lane < 38) {
                    d0 = __hip_atomic_load(&trow[2 * lane],
                                           __ATOMIC_RELAXED, __HIP_MEMORY_SCOPE_AGENT);
                    d1 = __hip_atomic_load(&trow[2 * lane + 1],
                                           __ATOMIC_RELAXED, __HIP_MEMORY_SCOPE_AGENT);
                }
                float bp = 0.f;
                if (act) {
                    const unsigned int hb = (unsigned int)(tv >> 32);
                    __builtin_memcpy(&bp, &hb, 4);
                }
                bp += __shfl_xor(bp, 1);
                bp += __shfl_xor(bp, 2);
                bp += __shfl_xor(bp, 4);
                if (lane == 0) betas[i - 1] = __shfl(bp, 0);

                if (lane < 38) {
                    uint4 q;
                    q.x = (unsigned int)d0; q.y = (unsigned int)(d0 >> 32);
                    q.z = (unsigned int)d1; q.w = (unsigned int)(d1 >> 32);
                    *(uint4*)&histp[(i - 1) * 152 + 4 * lane] = q;
                }
            } else if (isv) {
                // ---- V-loop over j <= i-2 with precomputed unnormalized weights ----
                #pragma unroll 4
                for (int j = 0; j + 1 < i; ++j) {
                    const float wj = wsm2[j];
                    const unsigned int u = histp[j * 152 + vt];
                    __half2 h; __builtin_memcpy(&h, &u, 4);
                    V0 = fmaf(wj, __half2float(h.x), V0);
                    V1 = fmaf(wj, __half2float(h.y), V1);
                }
            }
            __syncthreads();   // B1

            if (isv) {
                const float beta_new = betas[i - 1];
                const float mxl = mx2s;
                float S = S_pres, e;
                if (beta_new > mxl) {
                    const float sc = __expf(mxl - beta_new);
                    V0 *= sc; V1 *= sc; S *= sc; e = 1.f;
                } else {
                    e = __expf(beta_new - mxl);
                }
                const unsigned int u = histp[(i - 1) * 152 + vt];
                __half2 h; __builtin_memcpy(&h, &u, 4);
                S += e;
                V0 = fmaf(e, __half2float(h.x), V0);
                V1 = fmaf(e, __half2float(h.y), V1);
                const float inv = 1.f / S;
                const float m0 = V0 * inv, m1 = V1 * inv;
                Mlds[2 * vt] = m0;
                Mlds[2 * vt + 1] = m1;
                M2[vt] = packh2(m0, m1);
            }
        } else {
            if (tid < DH) Mlds[tid] = 0.f;
        }
        __syncthreads();   // B4

        // ---- matvec (scan9 form: full K per thread, scratch-backed w[]) ----
        if (tid < ROWS) {
            float a0 = 0.f, a1 = 0.f;
            #pragma unroll
            for (int j4 = 0; j4 < 152; j4 += 4) {
                const uint4 m4 = *(const uint4*)&M2[j4];
                a0 = dot2f(m4.x, w[j4 + 0], a0);
                a1 = dot2f(m4.y, w[j4 + 1], a1);
                a0 = dot2f(m4.z, w[j4 + 2], a0);
                a1 = dot2f(m4.w, w[j4 + 3], a1);
            }
            gmv[tid] = a0 + a1;
        }
        __syncthreads();   // B5

        // ---- gates + per-wave early release (waves 0-1) || prep next softmax (wave 2) ----
        if (wid < 2) {
            float rowv = 0.f;
            if (tid < swk) {
                const float Mi = Mlds[D];
                const float hc0 = gmv[0 * swk + tid] + cb0;
                const float hc1 = gmv[1 * swk + tid] + cb1;
                const float hc2 = gmv[2 * swk + tid] + cb2;
                const float rc = sigmoidf_(gi0 + hc0);
                const float zc = sigmoidf_(gi1 + hc1);
                const float nc = tanh_fast(gi2 + rc * hc2);
                const float Cc = (1.f - zc) * nc + zc * Mi;
                const float ip0 = gmv[3 * swk + tid] + pb0;
                const float ip1 = gmv[4 * swk + tid] + pb1;
                const float ip2 = gmv[5 * swk + tid] + pb2;
                const float rp = sigmoidf_(ip0 + gp0);
                const float zp = sigmoidf_(ip1 + gp1);
                const float np = tanh_fast(ip2 + rp * gp2);
                const float Pp = (1.f - zp) * np + zp * xi;
                rowv = Cc + Pp;
            }
            const float pr = __shfl_xor(rowv, 1);
            const unsigned int pairu32 = packh2(rowv, pr);
            if (tid < swk && !(tid & 1)) {
                __hip_atomic_store(&mb32[(long)i * (MROW * 2) + 38 * k + (tid >> 1)], pairu32,
                                   __ATOMIC_RELAXED, __HIP_MEMORY_SCOPE_AGENT);
                if (l == 0)   // packed A row for the layer-1 fused GEMM (plain store)
                    APKN[((long)b * NB + i) * 160 + 38 * k + (tid >> 1)] = pairu32;
            }
            float bv = (tid < swk) ? rowv * wkD : 0.f;
            #pragma unroll
            for (int off = 32; off; off >>= 1) bv += __shfl_xor(bv, off);
            asm volatile("s_waitcnt vmcnt(0)" ::: "memory");
            if (lane == 0) {
                unsigned int bbits;
                __builtin_memcpy(&bbits, &bv, 4);
                const unsigned long long pkt =
                    ((unsigned long long)bbits << 32) | (unsigned int)(i + 1);
                __hip_atomic_store(&mb[(long)i * MROW + 152 + 2 * k + wid], pkt,
                                   __ATOMIC_RELAXED, __HIP_MEMORY_SCOPE_AGENT);
            }
            if (tid < swk) ycol[(long)i * OUTD + D] = rowv;
        } else if (wid == 2 && i + 1 < NB) {
            const int j1 = lane + 64;
            const bool v0 = (lane < i) && (a0p != 0);
            const bool v1 = (j1 < i) && (a1p != 0);
            const float aa0 = v0 ? betas[lane] : -3.0e38f;
            const float aa1 = v1 ? betas[j1]   : -3.0e38f;
            float mx = fmaxf(aa0, aa1);
            #pragma unroll
            for (int off = 32; off; off >>= 1) mx = fmaxf(mx, __shfl_xor(mx, off));
            const float e0 = v0 ? __expf(aa0 - mx) : 0.f;
            const float e1 = v1 ? __expf(aa1 - mx) : 0.f;
            float s = e0 + e1;
            #pragma unroll
            for (int off = 32; off; off >>= 1) s += __shfl_xor(s, off);
            wsm2[lane] = e0;
            wsm2[j1]   = e1;
            if (lane == 0) { mx2s = mx; S_pres = s; }
        }
        __syncthreads();   // B6
    }
}

extern "C" void kernel_launch(void* const* d_in, const int* in_sizes, int n_in,
                              void* d_out, int out_size, void* d_ws, size_t ws_size,
                              hipStream_t stream) {
    (void)in_sizes; (void)n_in; (void)out_size; (void)ws_size;
    const float* features = (const float*)d_in[0];
    const float* fc1_w    = (const float*)d_in[1];
    const float* fc1_b    = (const float*)d_in[2];
    const float* gat_w    = (const float*)d_in[3];
    const float* gc_wih   = (const float*)d_in[5];
    const float* gc_whh   = (const float*)d_in[6];
    const float* gc_bih   = (const float*)d_in[7];
    const float* gc_bhh   = (const float*)d_in[8];
    const float* gp_wih   = (const float*)d_in[9];
    const float* gp_whh   = (const float*)d_in[10];
    const float* gp_bih   = (const float*)d_in[11];
    const float* gp_bhh   = (const float*)d_in[12];
    const int*   adj      = (const int*)d_in[13];
    float* out = (float*)d_out;

    unsigned long long* TB = (unsigned long long*)d_ws;            // 2*64*128*160 u64
    float* GG = (float*)(TB + 2L * B_ * NB * MROW);                // 8192*1800 f32
    unsigned int* PK2  = (unsigned int*)(GG + 8192L * G6);          // 2*150*1800
    unsigned int* APK2 = PK2 + 2 * 150 * PK_STRIDE;                 // 8192*160
    unsigned int* BPKF = APK2 + 8192L * 160;                        // 320*512
    unsigned int* BPKL = BPKF + 320L * 512;                         // 2*1856*160
    unsigned int* APK1 = (unsigned int*)GG;                         // alias (fc1 A; dead before GG written)

    hipFuncSetAttribute(reinterpret_cast<const void*>(scan14),
                        hipFuncAttributeMaxDynamicSharedMemorySize, 80000);
    hipMemsetAsync(TB, 0, 2L * B_ * NB * MROW * sizeof(unsigned long long), stream);
    hipMemsetAsync(APK2, 0, 8192L * 160 * sizeof(unsigned int), stream);   // pad cols 150-159 stay 0

    copy_feat<<<dim3((B_ * NB * E_) / 1024), 256, 0, stream>>>(features, out);
    pack2<<<dim3((2 * 150 * PK_STRIDE + 255) / 256), 256, 0, stream>>>(gc_whh, gp_wih, PK2);

    pack_af<<<dim3(8192 * 512 / 256), 256, 0, stream>>>(features, APK1);
    pack_bf<<<dim3(320 * 512 / 256), 256, 0, stream>>>(fc1_w, BPKF);
    pack_bw2<<<dim3((2 * BROWS * 160 + 255) / 256), 256, 0, stream>>>(gc_wih, gp_whh, BPKL);

    // H0 = relu(features @ fc1_w + b) -> out cols [0,300) f32 + APK2 packed f16
    gemm_h16<1, 1><<<dim3(5, 64), 256, 0, stream>>>(
        APK1, 512, BPKF, 512, fc1_b, fc1_b, DH, out, OUTD, APK2, 160, DH, 512);

    for (int l = 0; l < 2; ++l) {
        // fused gate-input GEMM: C[8192][1800] = A @ [cwih; pwhh]^T + [bih; bhh]
        gemm_h16<0, 0><<<dim3(29, 64), 256, 0, stream>>>(
            APK2, 160, BPKL + (long)l * BROWS * 160, 160,
            gc_bih + l * G3, gp_bhh + l * G3, G3,
            GG, G6, (unsigned int*)nullptr, 0, G6, 160);
        scan14<<<dim3(SLICES * B_), 512, 77824, stream>>>(
            out, GG, PK2 + (long)l * 150 * PK_STRIDE,
            gc_bhh + l * G3, gp_bih + l * G3, adj,
            gat_w + l * 2 * DH + DH,
            TB + (long)l * B_ * NB * MROW,
            APK2, l);
    }
}

// Round 15
// 1098.650 us; speedup vs baseline: 1.9222x; 1.0682x over previous
//
#include <hip/hip_runtime.h>
#include <hip/hip_fp16.h>

#define B_   64
#define NB   128
#define E_   1024
#define DH   300
#define G3   900
#define G6   1800
#define OUTD 1924
#define SLICES 4
#define PK_STRIDE 1800
#define MROW 160   // u64/row: u32 data words [0..149], tag u64s [152..159]
#define BROWS 1856 // padded B rows for fused layer GEMM

typedef _Float16 h2raw __attribute__((ext_vector_type(2)));
typedef _Float16 f16x8 __attribute__((ext_vector_type(8)));
typedef float f32x4 __attribute__((ext_vector_type(4)));

__device__ __forceinline__ float dot2f(unsigned int m2, unsigned int w, float acc) {
    h2raw a, b;
    __builtin_memcpy(&a, &m2, 4);
    __builtin_memcpy(&b, &w, 4);
    return __builtin_amdgcn_fdot2(a, b, acc, false);
}

__device__ __forceinline__ unsigned int packh2(float x, float y) {
    __half2 h;
    h.x = __float2half_rn(x);
    h.y = __float2half_rn(y);
    unsigned int u;
    __builtin_memcpy(&u, &h, 4);
    return u;
}

__device__ __forceinline__ float sigmoidf_(float x) { return 1.f / (1.f + __expf(-x)); }
__device__ __forceinline__ float tanh_fast(float x) { return 1.f - 2.f / (__expf(2.f * x) + 1.f); }

// ---------------- copy features into output tail ----------------
__global__ __launch_bounds__(256)
void copy_feat(const float* __restrict__ f, float* __restrict__ out) {
    const long id = (long)blockIdx.x * 256 + threadIdx.x;
    const long r = id >> 8;
    const int  c = (int)(id & 255);
    const float4 v = ((const float4*)(f + r * E_))[c];
    ((float4*)(out + r * OUTD + 3 * DH))[c] = v;
}

// ---------------- pack recurrent weights -> PK2[l][kp(150)][R(1800)] f16-pairs (kp-major) ----------------
__global__ __launch_bounds__(256)
void pack2(const float* __restrict__ gc_whh, const float* __restrict__ gp_wih,
           unsigned int* __restrict__ dst) {
    const int id = blockIdx.x * 256 + threadIdx.x;
    if (id >= 2 * 150 * PK_STRIDE) return;
    const int l   = id / (150 * PK_STRIDE);
    const int rem = id % (150 * PK_STRIDE);
    const int kp  = rem / PK_STRIDE;
    const int R   = rem % PK_STRIDE;
    const int mat = R / G3;
    const int o   = R % G3;
    const float* W = (mat ? gp_wih : gc_whh) + (long)l * G3 * DH;
    const float2 v = *(const float2*)(W + (long)o * DH + 2 * kp);
    dst[id] = packh2(v.x, v.y);
}

// ---------------- GEMM input packing ----------------
__global__ __launch_bounds__(256)
void pack_af(const float* __restrict__ src, unsigned int* __restrict__ dst) {
    const long id = (long)blockIdx.x * 256 + threadIdx.x;   // 8192*512
    const long r = id >> 9;
    const int kp = (int)(id & 511);
    const float2 v = *(const float2*)(src + r * E_ + 2 * kp);
    dst[id] = packh2(v.x, v.y);
}

__global__ __launch_bounds__(256)
void pack_bf(const float* __restrict__ W, unsigned int* __restrict__ dst) {
    const int id = blockIdx.x * 256 + threadIdx.x;          // 320*512
    const int n = id >> 9;
    const int kp = id & 511;
    unsigned int u = 0u;
    if (n < DH) u = packh2(W[(2 * kp) * DH + n], W[(2 * kp + 1) * DH + n]);
    dst[id] = u;
}

// fused layer-B pack: rows 0..899 = cwih, 900..1799 = pwhh, rest zero -> [BROWS][160]
__global__ __launch_bounds__(256)
void pack_bw2(const float* __restrict__ Wc, const float* __restrict__ Wp,
              unsigned int* __restrict__ dst) {
    const int id = blockIdx.x * 256 + threadIdx.x;
    if (id >= 2 * BROWS * 160) return;
    const int l   = id / (BROWS * 160);
    const int rem = id % (BROWS * 160);
    const int n   = rem / 160;
    const int kp  = rem % 160;
    unsigned int u = 0u;
    if (n < G6 && kp < 150) {
        const float* W = (n < G3 ? Wc : Wp) + (long)l * G3 * DH;
        const int o = (n < G3) ? n : n - G3;
        const float2 v = *(const float2*)(W + (long)o * DH + 2 * kp);
        u = packh2(v.x, v.y);
    }
    dst[id] = u;
}

// ---------------- MFMA f16 GEMM: per-wave 32x64 C tile, fragments straight from L2 ----------------
// APK [M][ldap] u32-pairs (8 f16 per uint4 = one fragment); BPK [Npad][ldbp] (B^T layout).
// A-frag: row m0+(lane&15), kp lane>>4 *4. B-frag: row n0+(lane&15), same kp. C: col=lane&15,
// row=(lane>>4)*4+reg (gfx950-verified mapping).
__device__ __forceinline__ f16x8 ldfrag(const unsigned int* p) {
    const uint4 u = *(const uint4*)p;
    f16x8 r;
    __builtin_memcpy(&r, &u, 16);
    return r;
}

template<int RELU, int PACKOUT>
__global__ __launch_bounds__(256)
void gemm_mf(const unsigned int* __restrict__ APK, int ldap,
             const unsigned int* __restrict__ BPK, int ldbp,
             const float* __restrict__ bias1, const float* __restrict__ bias2, int bsplit,
             float* __restrict__ C, int ldc,
             unsigned int* __restrict__ CPK, int ldcp,
             int N, int KSTEPS)
{
    const int lane = threadIdx.x & 63;
    const int wv = threadIdx.x >> 6;
    const int m0 = blockIdx.y * 128 + wv * 32;
    const int n0 = blockIdx.x * 64;
    const int ln = lane & 15;
    const int lh = lane >> 4;

    const unsigned int* a0p = APK + (long)(m0 + ln) * ldap + lh * 4;
    const unsigned int* a1p = a0p + 16L * ldap;
    const unsigned int* b0p = BPK + (long)(n0 + ln) * ldbp + lh * 4;

    f32x4 acc[2][4];
    #pragma unroll
    for (int mi = 0; mi < 2; ++mi)
        #pragma unroll
        for (int bj = 0; bj < 4; ++bj)
            acc[mi][bj] = (f32x4){0.f, 0.f, 0.f, 0.f};

    for (int ks = 0; ks < KSTEPS; ++ks) {
        const int off = ks * 16;
        const f16x8 a0 = ldfrag(a0p + off);
        const f16x8 a1 = ldfrag(a1p + off);
        const f16x8 b0 = ldfrag(b0p + off);
        const f16x8 b1 = ldfrag(b0p + 16L * ldbp + off);
        const f16x8 b2 = ldfrag(b0p + 32L * ldbp + off);
        const f16x8 b3 = ldfrag(b0p + 48L * ldbp + off);
        acc[0][0] = __builtin_amdgcn_mfma_f32_16x16x32_f16(a0, b0, acc[0][0], 0, 0, 0);
        acc[0][1] = __builtin_amdgcn_mfma_f32_16x16x32_f16(a0, b1, acc[0][1], 0, 0, 0);
        acc[0][2] = __builtin_amdgcn_mfma_f32_16x16x32_f16(a0, b2, acc[0][2], 0, 0, 0);
        acc[0][3] = __builtin_amdgcn_mfma_f32_16x16x32_f16(a0, b3, acc[0][3], 0, 0, 0);
        acc[1][0] = __builtin_amdgcn_mfma_f32_16x16x32_f16(a1, b0, acc[1][0], 0, 0, 0);
        acc[1][1] = __builtin_amdgcn_mfma_f32_16x16x32_f16(a1, b1, acc[1][1], 0, 0, 0);
        acc[1][2] = __builtin_amdgcn_mfma_f32_16x16x32_f16(a1, b2, acc[1][2], 0, 0, 0);
        acc[1][3] = __builtin_amdgcn_mfma_f32_16x16x32_f16(a1, b3, acc[1][3], 0, 0, 0);
    }

    #pragma unroll
    for (int mi = 0; mi < 2; ++mi) {
        #pragma unroll
        for (int bj = 0; bj < 4; ++bj) {
            const int gcol = n0 + bj * 16 + ln;
            #pragma unroll
            for (int r = 0; r < 4; ++r) {
                const int gm = m0 + mi * 16 + lh * 4 + r;
                float v = acc[mi][bj][r];
                if (gcol < N) v += (gcol < bsplit) ? bias1[gcol] : bias2[gcol - bsplit];
                if (RELU) v = fmaxf(v, 0.f);
                const float pr = PACKOUT ? __shfl_xor(v, 1) : 0.f;
                if (gcol < N) {
                    C[(long)gm * ldc + gcol] = v;
                    if (PACKOUT && !(ln & 1))
                        CPK[(long)gm * ldcp + (gcol >> 1)] = packh2(v, pr);
                }
            }
        }
    }
}

// ---------------- DAG scan v14 (proven): fused GG buffer + packed-A side-write ----------------
__global__ __launch_bounds__(512, 2)
void scan14(float* __restrict__ out,
            const float* __restrict__ GG,          // [8192][1800]: cols 0-899 gi_c, 900-1799 gh_p
            const unsigned int* __restrict__ PK2L, // kp-major [150][1800]
            const float* __restrict__ cbhh,
            const float* __restrict__ pbih,
            const int* __restrict__ adj,
            const float* __restrict__ wk,
            unsigned long long* __restrict__ TBL,
            unsigned int* __restrict__ APKN,       // packed A for next layer (l==0), else unused
            int l)
{
    extern __shared__ unsigned int histp[];   // [128][152] f16-pairs
    __shared__ float wsm2[NB];
    __shared__ float betas[NB];
    __shared__ float Mlds[DH];
    __shared__ __align__(16) unsigned int M2[152];
    __shared__ float gmv[456];
    __shared__ float mx2s, S_pres;

    const int tid = threadIdx.x;
    const int lane = tid & 63;
    const int wid = tid >> 6;
    const int b = blockIdx.x & 63;
    const int k = blockIdx.x >> 6;
    const int swk = (k == 3) ? 72 : 76;

    float* outb = out + (long)b * NB * OUTD;
    const float* xcol = outb + l * DH;
    float* ycol = outb + (l + 1) * DH;
    const float* ggb = GG + (long)b * NB * G6;
    const int* adjb = adj + b * NB * NB;
    unsigned long long* mb = TBL + (long)b * NB * MROW;
    unsigned int* mb32 = (unsigned int*)mb;

    if (tid < 152) M2[tid] = 0u;

    const int D = 76 * k + ((tid < swk) ? tid : 0);
    const float cb0 = cbhh[D], cb1 = cbhh[DH + D], cb2 = cbhh[2 * DH + D];
    const float pb0 = pbih[D], pb1 = pbih[DH + D], pb2 = pbih[2 * DH + D];
    const float wkD = wk[D];

    const int ROWS = 6 * swk;
    int R;
    {
        const int t = (tid < ROWS) ? tid : 0;
        const int d = t % swk;
        const int r = t / swk;
        R = (r / 3) * G3 + (r % 3) * DH + 76 * k + d;
    }
    unsigned int w[152];
    #pragma unroll
    for (int j = 0; j < 150; ++j) w[j] = PK2L[j * PK_STRIDE + R];
    w[150] = 0u; w[151] = 0u;

    __syncthreads();

    const bool isv = (tid >= 256) && (tid < 406);
    const int vt = tid - 256;

    for (int i = 0; i < NB; ++i) {
        // ---- top-of-step prefetches ----
        float gi0 = 0, gi1 = 0, gi2 = 0, gp0 = 0, gp1 = 0, gp2 = 0, xi = 0;
        if (tid < swk) {
            const float* gic = ggb + (long)i * G6;
            gi0 = gic[D]; gi1 = gic[DH + D]; gi2 = gic[2 * DH + D];
            gp0 = gic[G3 + D]; gp1 = gic[G3 + DH + D]; gp2 = gic[G3 + 2 * DH + D];
            xi = xcol[(long)i * OUTD + D];
        }
        int a0p = 0, a1p = 0;
        if (wid == 2 && i + 1 < NB) {
            a0p = adjb[(i + 1) * NB + lane];
            a1p = adjb[(i + 1) * NB + 64 + lane];
        }

        if (i > 0) {
            float V0 = 0.f, V1 = 0.f;
            if (wid == 0) {
                // ---- poll 8 self-describing tag words ----
                const unsigned long long* trow = mb + (long)(i - 1) * MROW;
                const unsigned int tag = (unsigned int)i;
                const bool act = (lane < 8);
                unsigned long long tv = 0;
                while (true) {
                    if (act && (unsigned int)tv != tag)
                        tv = __hip_atomic_load(&trow[152 + lane],
                                               __ATOMIC_RELAXED, __HIP_MEMORY_SCOPE_AGENT);
                    if (__all(!act || (unsigned int)tv == tag)) break;
                }
                unsigned long long d0 = 0, d1 = 0;
                if (lane < 38) {
                    d0 = __hip_atomic_load(&trow[2 * lane],
                                           __ATOMIC_RELAXED, __HIP_MEMORY_SCOPE_AGENT);
                    d1 = __hip_atomic_load(&trow[2 * lane + 1],
                                           __ATOMIC_RELAXED, __HIP_MEMORY_SCOPE_AGENT);
                }
                float bp = 0.f;
                if (act) {
                    const unsigned int hb = (unsigned int)(tv >> 32);
                    __builtin_memcpy(&bp, &hb, 4);
                }
                bp += __shfl_xor(bp, 1);
                bp += __shfl_xor(bp, 2);
                bp += __shfl_xor(bp, 4);
                if (lane == 0) betas[i - 1] = __shfl(bp, 0);

                if (lane < 38) {
                    uint4 q;
                    q.x = (unsigned int)d0; q.y = (unsigned int)(d0 >> 32);
                    q.z = (unsigned int)d1; q.w = (unsigned int)(d1 >> 32);
                    *(uint4*)&histp[(i - 1) * 152 + 4 * lane] = q;
                }
            } else if (isv) {
                // ---- V-loop over j <= i-2 with precomputed unnormalized weights ----
                #pragma unroll 4
                for (int j = 0; j + 1 < i; ++j) {
                    const float wj = wsm2[j];
                    const unsigned int u = histp[j * 152 + vt];
                    __half2 h; __builtin_memcpy(&h, &u, 4);
                    V0 = fmaf(wj, __half2float(h.x), V0);
                    V1 = fmaf(wj, __half2float(h.y), V1);
                }
            }
            __syncthreads();   // B1

            if (isv) {
                const float beta_new = betas[i - 1];
                const float mxl = mx2s;
                float S = S_pres, e;
                if (beta_new > mxl) {
                    const float sc = __expf(mxl - beta_new);
                    V0 *= sc; V1 *= sc; S *= sc; e = 1.f;
                } else {
                    e = __expf(beta_new - mxl);
                }
                const unsigned int u = histp[(i - 1) * 152 + vt];
                __half2 h; __builtin_memcpy(&h, &u, 4);
                S += e;
                V0 = fmaf(e, __half2float(h.x), V0);
                V1 = fmaf(e, __half2float(h.y), V1);
                const float inv = 1.f / S;
                const float m0 = V0 * inv, m1 = V1 * inv;
                Mlds[2 * vt] = m0;
                Mlds[2 * vt + 1] = m1;
                M2[vt] = packh2(m0, m1);
            }
        } else {
            if (tid < DH) Mlds[tid] = 0.f;
        }
        __syncthreads();   // B4

        // ---- matvec (scan9 form: full K per thread, scratch-backed w[]) ----
        if (tid < ROWS) {
            float a0 = 0.f, a1 = 0.f;
            #pragma unroll
            for (int j4 = 0; j4 < 152; j4 += 4) {
                const uint4 m4 = *(const uint4*)&M2[j4];
                a0 = dot2f(m4.x, w[j4 + 0], a0);
                a1 = dot2f(m4.y, w[j4 + 1], a1);
                a0 = dot2f(m4.z, w[j4 + 2], a0);
                a1 = dot2f(m4.w, w[j4 + 3], a1);
            }
            gmv[tid] = a0 + a1;
        }
        __syncthreads();   // B5

        // ---- gates + per-wave early release (waves 0-1) || prep next softmax (wave 2) ----
        if (wid < 2) {
            float rowv = 0.f;
            if (tid < swk) {
                const float Mi = Mlds[D];
                const float hc0 = gmv[0 * swk + tid] + cb0;
                const float hc1 = gmv[1 * swk + tid] + cb1;
                const float hc2 = gmv[2 * swk + tid] + cb2;
                const float rc = sigmoidf_(gi0 + hc0);
                const float zc = sigmoidf_(gi1 + hc1);
                const float nc = tanh_fast(gi2 + rc * hc2);
                const float Cc = (1.f - zc) * nc + zc * Mi;
                const float ip0 = gmv[3 * swk + tid] + pb0;
                const float ip1 = gmv[4 * swk + tid] + pb1;
                const float ip2 = gmv[5 * swk + tid] + pb2;
                const float rp = sigmoidf_(ip0 + gp0);
                const float zp = sigmoidf_(ip1 + gp1);
                const float np = tanh_fast(ip2 + rp * gp2);
                const float Pp = (1.f - zp) * np + zp * xi;
                rowv = Cc + Pp;
            }
            const float pr = __shfl_xor(rowv, 1);
            const unsigned int pairu32 = packh2(rowv, pr);
            if (tid < swk && !(tid & 1)) {
                __hip_atomic_store(&mb32[(long)i * (MROW * 2) + 38 * k + (tid >> 1)], pairu32,
                                   __ATOMIC_RELAXED, __HIP_MEMORY_SCOPE_AGENT);
                if (l == 0)   // packed A row for the layer-1 fused GEMM (plain store)
                    APKN[((long)b * NB + i) * 160 + 38 * k + (tid >> 1)] = pairu32;
            }
            float bv = (tid < swk) ? rowv * wkD : 0.f;
            #pragma unroll
            for (int off = 32; off; off >>= 1) bv += __shfl_xor(bv, off);
            asm volatile("s_waitcnt vmcnt(0)" ::: "memory");
            if (lane == 0) {
                unsigned int bbits;
                __builtin_memcpy(&bbits, &bv, 4);
                const unsigned long long pkt =
                    ((unsigned long long)bbits << 32) | (unsigned int)(i + 1);
                __hip_atomic_store(&mb[(long)i * MROW + 152 + 2 * k + wid], pkt,
                                   __ATOMIC_RELAXED, __HIP_MEMORY_SCOPE_AGENT);
            }
            if (tid < swk) ycol[(long)i * OUTD + D] = rowv;
        } else if (wid == 2 && i + 1 < NB) {
            const int j1 = lane + 64;
            const bool v0 = (lane < i) && (a0p != 0);
            const bool v1 = (j1 < i) && (a1p != 0);
            const float aa0 = v0 ? betas[lane] : -3.0e38f;
            const float aa1 = v1 ? betas[j1]   : -3.0e38f;
            float mx = fmaxf(aa0, aa1);
            #pragma unroll
            for (int off = 32; off; off >>= 1) mx = fmaxf(mx, __shfl_xor(mx, off));
            const float e0 = v0 ? __expf(aa0 - mx) : 0.f;
            const float e1 = v1 ? __expf(aa1 - mx) : 0.f;
            float s = e0 + e1;
            #pragma unroll
            for (int off = 32; off; off >>= 1) s += __shfl_xor(s, off);
            wsm2[lane] = e0;
            wsm2[j1]   = e1;
            if (lane == 0) { mx2s = mx; S_pres = s; }
        }
        __syncthreads();   // B6
    }
}

extern "C" void kernel_launch(void* const* d_in, const int* in_sizes, int n_in,
                              void* d_out, int out_size, void* d_ws, size_t ws_size,
                              hipStream_t stream) {
    (void)in_sizes; (void)n_in; (void)out_size; (void)ws_size;
    const float* features = (const float*)d_in[0];
    const float* fc1_w    = (const float*)d_in[1];
    const float* fc1_b    = (const float*)d_in[2];
    const float* gat_w    = (const float*)d_in[3];
    const float* gc_wih   = (const float*)d_in[5];
    const float* gc_whh   = (const float*)d_in[6];
    const float* gc_bih   = (const float*)d_in[7];
    const float* gc_bhh   = (const float*)d_in[8];
    const float* gp_wih   = (const float*)d_in[9];
    const float* gp_whh   = (const float*)d_in[10];
    const float* gp_bih   = (const float*)d_in[11];
    const float* gp_bhh   = (const float*)d_in[12];
    const int*   adj      = (const int*)d_in[13];
    float* out = (float*)d_out;

    unsigned long long* TB = (unsigned long long*)d_ws;            // 2*64*128*160 u64
    float* GG = (float*)(TB + 2L * B_ * NB * MROW);                // 8192*1800 f32
    unsigned int* PK2  = (unsigned int*)(GG + 8192L * G6);          // 2*150*1800
    unsigned int* APK2 = PK2 + 2 * 150 * PK_STRIDE;                 // 8192*160
    unsigned int* BPKF = APK2 + 8192L * 160;                        // 320*512
    unsigned int* BPKL = BPKF + 320L * 512;                         // 2*1856*160
    unsigned int* APK1 = (unsigned int*)GG;                         // alias (fc1 A; dead before GG written)

    hipFuncSetAttribute(reinterpret_cast<const void*>(scan14),
                        hipFuncAttributeMaxDynamicSharedMemorySize, 80000);
    hipMemsetAsync(TB, 0, 2L * B_ * NB * MROW * sizeof(unsigned long long), stream);
    hipMemsetAsync(APK2, 0, 8192L * 160 * sizeof(unsigned int), stream);   // pad cols 150-159 stay 0

    copy_feat<<<dim3((B_ * NB * E_) / 1024), 256, 0, stream>>>(features, out);
    pack2<<<dim3((2 * 150 * PK_STRIDE + 255) / 256), 256, 0, stream>>>(gc_whh, gp_wih, PK2);

    pack_af<<<dim3(8192 * 512 / 256), 256, 0, stream>>>(features, APK1);
    pack_bf<<<dim3(320 * 512 / 256), 256, 0, stream>>>(fc1_w, BPKF);
    pack_bw2<<<dim3((2 * BROWS * 160 + 255) / 256), 256, 0, stream>>>(gc_wih, gp_whh, BPKL);

    // H0 = relu(features @ fc1_w + b) -> out cols [0,300) f32 + APK2 packed f16 (MFMA)
    gemm_mf<1, 1><<<dim3(5, 64), 256, 0, stream>>>(
        APK1, 512, BPKF, 512, fc1_b, fc1_b, DH, out, OUTD, APK2, 160, DH, 32);

    for (int l = 0; l < 2; ++l) {
        // fused gate-input GEMM: C[8192][1800] = A @ [cwih; pwhh]^T + [bih; bhh] (MFMA)
        gemm_mf<0, 0><<<dim3(29, 64), 256, 0, stream>>>(
            APK2, 160, BPKL + (long)l * BROWS * 160, 160,
            gc_bih + l * G3, gp_bhh + l * G3, G3,
            GG, G6, (unsigned int*)nullptr, 0, G6, 10);
        scan14<<<dim3(SLICES * B_), 512, 77824, stream>>>(
            out, GG, PK2 + (long)l * 150 * PK_STRIDE,
            gc_bhh + l * G3, gp_bih + l * G3, adj,
            gat_w + l * 2 * DH + DH,
            TB + (long)l * B_ * NB * MROW,
            APK2, l);
    }
}

// Round 16
// 1075.821 us; speedup vs baseline: 1.9630x; 1.0212x over previous
//
#include <hip/hip_runtime.h>
#include <hip/hip_fp16.h>

#define B_   64
#define NB   128
#define E_   1024
#define DH   300
#define G3   900
#define G6   1800
#define OUTD 1924
#define SLICES 4
#define PK_STRIDE 1800
#define MROW 160   // u64/row: u32 data words [0..149], tag u64s [152..159]
#define BROWS 1856 // padded B rows for fused layer GEMM

typedef _Float16 h2raw __attribute__((ext_vector_type(2)));
typedef _Float16 f16x8 __attribute__((ext_vector_type(8)));
typedef float f32x4 __attribute__((ext_vector_type(4)));

__device__ __forceinline__ float dot2f(unsigned int m2, unsigned int w, float acc) {
    h2raw a, b;
    __builtin_memcpy(&a, &m2, 4);
    __builtin_memcpy(&b, &w, 4);
    return __builtin_amdgcn_fdot2(a, b, acc, false);
}

__device__ __forceinline__ unsigned int packh2(float x, float y) {
    __half2 h;
    h.x = __float2half_rn(x);
    h.y = __float2half_rn(y);
    unsigned int u;
    __builtin_memcpy(&u, &h, 4);
    return u;
}

__device__ __forceinline__ float sigmoidf_(float x) { return 1.f / (1.f + __expf(-x)); }
__device__ __forceinline__ float tanh_fast(float x) { return 1.f - 2.f / (__expf(2.f * x) + 1.f); }

// ================= merged pack kernel: all input transforms in one launch =================
// seg A: pack2   -> PK2 [2][150][1800]    (kp-major recurrent weights)
// seg B: pack_af -> APK1 [8192][512]      (features f16 pairs)
// seg C: pack_bf -> BPKF [320][512]       (fc1_w^T pairs)
// seg D: pack_bw2-> BPKL [2][1856][160]   (fused layer-B)
// seg E: PK2T    -> [2][1800][76]         (row-contiguous resident half kp 0..75)
// seg F: copy_feat (float4 granules)
// seg G: APK2 pad cols 150..159 = 0
#define NA (2 * 150 * PK_STRIDE)
#define NB_SEG (8192 * 512)
#define NC (320 * 512)
#define ND (2 * BROWS * 160)
#define NE (2 * 1800 * 76)
#define NF (B_ * NB * 256)
#define NG (8192 * 10)
#define NTOT (NA + NB_SEG + NC + ND + NE + NF + NG)

__global__ __launch_bounds__(256)
void pack_all(const float* __restrict__ gc_whh, const float* __restrict__ gp_wih,
              const float* __restrict__ features, const float* __restrict__ fc1_w,
              const float* __restrict__ gc_wih, const float* __restrict__ gp_whh,
              unsigned int* __restrict__ PK2, unsigned int* __restrict__ APK1,
              unsigned int* __restrict__ BPKF, unsigned int* __restrict__ BPKL,
              unsigned int* __restrict__ PK2T, float* __restrict__ out,
              unsigned int* __restrict__ APK2)
{
    long id = (long)blockIdx.x * 256 + threadIdx.x;
    if (id >= NTOT) return;
    if (id < NA) {
        const int l   = (int)(id / (150 * PK_STRIDE));
        const int rem = (int)(id % (150 * PK_STRIDE));
        const int kp  = rem / PK_STRIDE;
        const int R   = rem % PK_STRIDE;
        const int mat = R / G3;
        const int o   = R % G3;
        const float* W = (mat ? gp_wih : gc_whh) + (long)l * G3 * DH;
        const float2 v = *(const float2*)(W + (long)o * DH + 2 * kp);
        PK2[id] = packh2(v.x, v.y);
        return;
    }
    id -= NA;
    if (id < NB_SEG) {
        const long r = id >> 9;
        const int kp = (int)(id & 511);
        const float2 v = *(const float2*)(features + r * E_ + 2 * kp);
        APK1[id] = packh2(v.x, v.y);
        return;
    }
    id -= NB_SEG;
    if (id < NC) {
        const int n = (int)(id >> 9);
        const int kp = (int)(id & 511);
        unsigned int u = 0u;
        if (n < DH) u = packh2(fc1_w[(2 * kp) * DH + n], fc1_w[(2 * kp + 1) * DH + n]);
        BPKF[id] = u;
        return;
    }
    id -= NC;
    if (id < ND) {
        const int l   = (int)(id / (BROWS * 160));
        const int rem = (int)(id % (BROWS * 160));
        const int n   = rem / 160;
        const int kp  = rem % 160;
        unsigned int u = 0u;
        if (n < G6 && kp < 150) {
            const float* W = (n < G3 ? gc_wih : gp_whh) + (long)l * G3 * DH;
            const int o = (n < G3) ? n : n - G3;
            const float2 v = *(const float2*)(W + (long)o * DH + 2 * kp);
            u = packh2(v.x, v.y);
        }
        BPKL[id] = u;
        return;
    }
    id -= ND;
    if (id < NE) {
        const int l   = (int)(id / (1800 * 76));
        const int rem = (int)(id % (1800 * 76));
        const int R   = rem / 76;
        const int kp  = rem % 76;
        const int mat = R / G3;
        const int o   = R % G3;
        const float* W = (mat ? gp_wih : gc_whh) + (long)l * G3 * DH;
        const float2 v = *(const float2*)(W + (long)o * DH + 2 * kp);
        PK2T[id] = packh2(v.x, v.y);
        return;
    }
    id -= NE;
    if (id < NF) {
        const long r = id >> 8;
        const int  c = (int)(id & 255);
        const float4 v = ((const float4*)(features + r * E_))[c];
        ((float4*)(out + r * OUTD + 3 * DH))[c] = v;
        return;
    }
    id -= NF;
    {   // APK2 pad columns
        const long r = id / 10;
        const int c = (int)(id % 10);
        APK2[r * 160 + 150 + c] = 0u;
    }
}

// ---------------- MFMA f16 GEMM: per-wave 32x64 C tile, fragments straight from L2 ----------------
__device__ __forceinline__ f16x8 ldfrag(const unsigned int* p) {
    const uint4 u = *(const uint4*)p;
    f16x8 r;
    __builtin_memcpy(&r, &u, 16);
    return r;
}

template<int RELU, int PACKOUT>
__global__ __launch_bounds__(256)
void gemm_mf(const unsigned int* __restrict__ APK, int ldap,
             const unsigned int* __restrict__ BPK, int ldbp,
             const float* __restrict__ bias1, const float* __restrict__ bias2, int bsplit,
             float* __restrict__ C, int ldc,
             unsigned int* __restrict__ CPK, int ldcp,
             int N, int KSTEPS)
{
    const int lane = threadIdx.x & 63;
    const int wv = threadIdx.x >> 6;
    const int m0 = blockIdx.y * 128 + wv * 32;
    const int n0 = blockIdx.x * 64;
    const int ln = lane & 15;
    const int lh = lane >> 4;

    const unsigned int* a0p = APK + (long)(m0 + ln) * ldap + lh * 4;
    const unsigned int* a1p = a0p + 16L * ldap;
    const unsigned int* b0p = BPK + (long)(n0 + ln) * ldbp + lh * 4;

    f32x4 acc[2][4];
    #pragma unroll
    for (int mi = 0; mi < 2; ++mi)
        #pragma unroll
        for (int bj = 0; bj < 4; ++bj)
            acc[mi][bj] = (f32x4){0.f, 0.f, 0.f, 0.f};

    for (int ks = 0; ks < KSTEPS; ++ks) {
        const int off = ks * 16;
        const f16x8 a0 = ldfrag(a0p + off);
        const f16x8 a1 = ldfrag(a1p + off);
        const f16x8 b0 = ldfrag(b0p + off);
        const f16x8 b1 = ldfrag(b0p + 16L * ldbp + off);
        const f16x8 b2 = ldfrag(b0p + 32L * ldbp + off);
        const f16x8 b3 = ldfrag(b0p + 48L * ldbp + off);
        acc[0][0] = __builtin_amdgcn_mfma_f32_16x16x32_f16(a0, b0, acc[0][0], 0, 0, 0);
        acc[0][1] = __builtin_amdgcn_mfma_f32_16x16x32_f16(a0, b1, acc[0][1], 0, 0, 0);
        acc[0][2] = __builtin_amdgcn_mfma_f32_16x16x32_f16(a0, b2, acc[0][2], 0, 0, 0);
        acc[0][3] = __builtin_amdgcn_mfma_f32_16x16x32_f16(a0, b3, acc[0][3], 0, 0, 0);
        acc[1][0] = __builtin_amdgcn_mfma_f32_16x16x32_f16(a1, b0, acc[1][0], 0, 0, 0);
        acc[1][1] = __builtin_amdgcn_mfma_f32_16x16x32_f16(a1, b1, acc[1][1], 0, 0, 0);
        acc[1][2] = __builtin_amdgcn_mfma_f32_16x16x32_f16(a1, b2, acc[1][2], 0, 0, 0);
        acc[1][3] = __builtin_amdgcn_mfma_f32_16x16x32_f16(a1, b3, acc[1][3], 0, 0, 0);
    }

    #pragma unroll
    for (int mi = 0; mi < 2; ++mi) {
        #pragma unroll
        for (int bj = 0; bj < 4; ++bj) {
            const int gcol = n0 + bj * 16 + ln;
            #pragma unroll
            for (int r = 0; r < 4; ++r) {
                const int gm = m0 + mi * 16 + lh * 4 + r;
                float v = acc[mi][bj][r];
                if (gcol < N) v += (gcol < bsplit) ? bias1[gcol] : bias2[gcol - bsplit];
                if (RELU) v = fmaxf(v, 0.f);
                const float pr = PACKOUT ? __shfl_xor(v, 1) : 0.f;
                if (gcol < N) {
                    C[(long)gm * ldc + gcol] = v;
                    if (PACKOUT && !(ln & 1))
                        CPK[(long)gm * ldcp + (gcol >> 1)] = packh2(v, pr);
                }
            }
        }
    }
}

// ---------------- DAG scan v16: scan14 + register-resident weight half (kp 0..75) ----------------
__global__ __launch_bounds__(512, 2)
void scan16(float* __restrict__ out,
            const float* __restrict__ GG,
            const unsigned int* __restrict__ PK2L,   // kp-major [150][1800]
            const unsigned int* __restrict__ PK2TL,  // row-major [1800][76] (kp 0..75)
            const float* __restrict__ cbhh,
            const float* __restrict__ pbih,
            const int* __restrict__ adj,
            const float* __restrict__ wk,
            unsigned long long* __restrict__ TBL,
            unsigned int* __restrict__ APKN,
            int l)
{
    extern __shared__ unsigned int histp[];   // [128][152] f16-pairs
    __shared__ float wsm2[NB];
    __shared__ float betas[NB];
    __shared__ float Mlds[DH];
    __shared__ __align__(16) unsigned int M2[152];
    __shared__ float gmv[456];
    __shared__ float mx2s, S_pres;

    const int tid = threadIdx.x;
    const int lane = tid & 63;
    const int wid = tid >> 6;
    const int b = blockIdx.x & 63;
    const int k = blockIdx.x >> 6;
    const int swk = (k == 3) ? 72 : 76;

    float* outb = out + (long)b * NB * OUTD;
    const float* xcol = outb + l * DH;
    float* ycol = outb + (l + 1) * DH;
    const float* ggb = GG + (long)b * NB * G6;
    const int* adjb = adj + b * NB * NB;
    unsigned long long* mb = TBL + (long)b * NB * MROW;
    unsigned int* mb32 = (unsigned int*)mb;

    if (tid < 152) M2[tid] = 0u;

    const int D = 76 * k + ((tid < swk) ? tid : 0);
    const float cb0 = cbhh[D], cb1 = cbhh[DH + D], cb2 = cbhh[2 * DH + D];
    const float pb0 = pbih[D], pb1 = pbih[DH + D], pb2 = pbih[2 * DH + D];
    const float wkD = wk[D];

    const int ROWS = 6 * swk;
    int R;
    {
        const int t = (tid < ROWS) ? tid : 0;
        const int d = t % swk;
        const int r = t / swk;
        R = (r / 3) * G3 + (r % 3) * DH + 76 * k + d;
    }
    // resident half: kp pairs 0..75, 19 uint4 held in VGPRs for the whole kernel
    uint4 wr[19];
    {
        const unsigned int* pkt = PK2TL + (long)R * 76;
        #pragma unroll
        for (int q = 0; q < 19; ++q) wr[q] = *(const uint4*)(pkt + 4 * q);
    }
    // streamed half: kp pairs 76..151 in scratch (re-read each step = the remaining streaming)
    unsigned int ws[76];
    #pragma unroll
    for (int j = 0; j < 76; ++j)
        ws[j] = (j < 74) ? PK2L[(76 + j) * PK_STRIDE + R] : 0u;   // pairs 150,151 zero

    __syncthreads();

    const bool isv = (tid >= 256) && (tid < 406);
    const int vt = tid - 256;

    for (int i = 0; i < NB; ++i) {
        // ---- top-of-step prefetches ----
        float gi0 = 0, gi1 = 0, gi2 = 0, gp0 = 0, gp1 = 0, gp2 = 0, xi = 0;
        if (tid < swk) {
            const float* gic = ggb + (long)i * G6;
            gi0 = gic[D]; gi1 = gic[DH + D]; gi2 = gic[2 * DH + D];
            gp0 = gic[G3 + D]; gp1 = gic[G3 + DH + D]; gp2 = gic[G3 + 2 * DH + D];
            xi = xcol[(long)i * OUTD + D];
        }
        int a0p = 0, a1p = 0;
        if (wid == 2 && i + 1 < NB) {
            a0p = adjb[(i + 1) * NB + lane];
            a1p = adjb[(i + 1) * NB + 64 + lane];
        }

        if (i > 0) {
            float V0 = 0.f, V1 = 0.f;
            if (wid == 0) {
                const unsigned long long* trow = mb + (long)(i - 1) * MROW;
                const unsigned int tag = (unsigned int)i;
                const bool act = (lane < 8);
                unsigned long long tv = 0;
                while (true) {
                    if (act && (unsigned int)tv != tag)
                        tv = __hip_atomic_load(&trow[152 + lane],
                                               __ATOMIC_RELAXED, __HIP_MEMORY_SCOPE_AGENT);
                    if (__all(!act || (unsigned int)tv == tag)) break;
                }
                unsigned long long d0 = 0, d1 = 0;
                if (lane < 38) {
                    d0 = __hip_atomic_load(&trow[2 * lane],
                                           __ATOMIC_RELAXED, __HIP_MEMORY_SCOPE_AGENT);
                    d1 = __hip_atomic_load(&trow[2 * lane + 1],
                                           __ATOMIC_RELAXED, __HIP_MEMORY_SCOPE_AGENT);
                }
                float bp = 0.f;
                if (act) {
                    const unsigned int hb = (unsigned int)(tv >> 32);
                    __builtin_memcpy(&bp, &hb, 4);
                }
                bp += __shfl_xor(bp, 1);
                bp += __shfl_xor(bp, 2);
                bp += __shfl_xor(bp, 4);
                if (lane == 0) betas[i - 1] = __shfl(bp, 0);

                if (lane < 38) {
                    uint4 q;
                    q.x = (unsigned int)d0; q.y = (unsigned int)(d0 >> 32);
                    q.z = (unsigned int)d1; q.w = (unsigned int)(d1 >> 32);
                    *(uint4*)&histp[(i - 1) * 152 + 4 * lane] = q;
                }
            } else if (isv) {
                #pragma unroll 4
                for (int j = 0; j + 1 < i; ++j) {
                    const float wj = wsm2[j];
                    const unsigned int u = histp[j * 152 + vt];
                    __half2 h; __builtin_memcpy(&h, &u, 4);
                    V0 = fmaf(wj, __half2float(h.x), V0);
                    V1 = fmaf(wj, __half2float(h.y), V1);
                }
            }
            __syncthreads();   // B1

            if (isv) {
                const float beta_new = betas[i - 1];
                const float mxl = mx2s;
                float S = S_pres, e;
                if (beta_new > mxl) {
                    const float sc = __expf(mxl - beta_new);
                    V0 *= sc; V1 *= sc; S *= sc; e = 1.f;
                } else {
                    e = __expf(beta_new - mxl);
                }
                const unsigned int u = histp[(i - 1) * 152 + vt];
                __half2 h; __builtin_memcpy(&h, &u, 4);
                S += e;
                V0 = fmaf(e, __half2float(h.x), V0);
                V1 = fmaf(e, __half2float(h.y), V1);
                const float inv = 1.f / S;
                const float m0 = V0 * inv, m1 = V1 * inv;
                Mlds[2 * vt] = m0;
                Mlds[2 * vt + 1] = m1;
                M2[vt] = packh2(m0, m1);
            }
        } else {
            if (tid < DH) Mlds[tid] = 0.f;
        }
        __syncthreads();   // B4

        // ---- matvec: kp 0..75 from resident registers, kp 76..151 streamed from scratch ----
        if (tid < ROWS) {
            float a0 = 0.f, a1 = 0.f;
            #pragma unroll
            for (int q = 0; q < 19; ++q) {
                const uint4 m4 = *(const uint4*)&M2[4 * q];
                a0 = dot2f(m4.x, wr[q].x, a0);
                a1 = dot2f(m4.y, wr[q].y, a1);
                a0 = dot2f(m4.z, wr[q].z, a0);
                a1 = dot2f(m4.w, wr[q].w, a1);
            }
            #pragma unroll
            for (int q = 0; q < 19; ++q) {
                const uint4 m4 = *(const uint4*)&M2[76 + 4 * q];
                const uint4 w4 = *(const uint4*)&ws[4 * q];
                a0 = dot2f(m4.x, w4.x, a0);
                a1 = dot2f(m4.y, w4.y, a1);
                a0 = dot2f(m4.z, w4.z, a0);
                a1 = dot2f(m4.w, w4.w, a1);
            }
            gmv[tid] = a0 + a1;
        }
        __syncthreads();   // B5

        // ---- gates + per-wave early release (waves 0-1) || prep next softmax (wave 2) ----
        if (wid < 2) {
            float rowv = 0.f;
            if (tid < swk) {
                const float Mi = Mlds[D];
                const float hc0 = gmv[0 * swk + tid] + cb0;
                const float hc1 = gmv[1 * swk + tid] + cb1;
                const float hc2 = gmv[2 * swk + tid] + cb2;
                const float rc = sigmoidf_(gi0 + hc0);
                const float zc = sigmoidf_(gi1 + hc1);
                const float nc = tanh_fast(gi2 + rc * hc2);
                const float Cc = (1.f - zc) * nc + zc * Mi;
                const float ip0 = gmv[3 * swk + tid] + pb0;
                const float ip1 = gmv[4 * swk + tid] + pb1;
                const float ip2 = gmv[5 * swk + tid] + pb2;
                const float rp = sigmoidf_(ip0 + gp0);
                const float zp = sigmoidf_(ip1 + gp1);
                const float np = tanh_fast(ip2 + rp * gp2);
                const float Pp = (1.f - zp) * np + zp * xi;
                rowv = Cc + Pp;
            }
            const float pr = __shfl_xor(rowv, 1);
            const unsigned int pairu32 = packh2(rowv, pr);
            if (tid < swk && !(tid & 1)) {
                __hip_atomic_store(&mb32[(long)i * (MROW * 2) + 38 * k + (tid >> 1)], pairu32,
                                   __ATOMIC_RELAXED, __HIP_MEMORY_SCOPE_AGENT);
                if (l == 0)
                    APKN[((long)b * NB + i) * 160 + 38 * k + (tid >> 1)] = pairu32;
            }
            float bv = (tid < swk) ? rowv * wkD : 0.f;
            #pragma unroll
            for (int off = 32; off; off >>= 1) bv += __shfl_xor(bv, off);
            asm volatile("s_waitcnt vmcnt(0)" ::: "memory");
            if (lane == 0) {
                unsigned int bbits;
                __builtin_memcpy(&bbits, &bv, 4);
                const unsigned long long pkt =
                    ((unsigned long long)bbits << 32) | (unsigned int)(i + 1);
                __hip_atomic_store(&mb[(long)i * MROW + 152 + 2 * k + wid], pkt,
                                   __ATOMIC_RELAXED, __HIP_MEMORY_SCOPE_AGENT);
            }
            if (tid < swk) ycol[(long)i * OUTD + D] = rowv;
        } else if (wid == 2 && i + 1 < NB) {
            const int j1 = lane + 64;
            const bool v0 = (lane < i) && (a0p != 0);
            const bool v1 = (j1 < i) && (a1p != 0);
            const float aa0 = v0 ? betas[lane] : -3.0e38f;
            const float aa1 = v1 ? betas[j1]   : -3.0e38f;
            float mx = fmaxf(aa0, aa1);
            #pragma unroll
            for (int off = 32; off; off >>= 1) mx = fmaxf(mx, __shfl_xor(mx, off));
            const float e0 = v0 ? __expf(aa0 - mx) : 0.f;
            const float e1 = v1 ? __expf(aa1 - mx) : 0.f;
            float s = e0 + e1;
            #pragma unroll
            for (int off = 32; off; off >>= 1) s += __shfl_xor(s, off);
            wsm2[lane] = e0;
            wsm2[j1]   = e1;
            if (lane == 0) { mx2s = mx; S_pres = s; }
        }
        __syncthreads();   // B6
    }
}

extern "C" void kernel_launch(void* const* d_in, const int* in_sizes, int n_in,
                              void* d_out, int out_size, void* d_ws, size_t ws_size,
                              hipStream_t stream) {
    (void)in_sizes; (void)n_in; (void)out_size; (void)ws_size;
    const float* features = (const float*)d_in[0];
    const float* fc1_w    = (const float*)d_in[1];
    const float* fc1_b    = (const float*)d_in[2];
    const float* gat_w    = (const float*)d_in[3];
    const float* gc_wih   = (const float*)d_in[5];
    const float* gc_whh   = (const float*)d_in[6];
    const float* gc_bih   = (const float*)d_in[7];
    const float* gc_bhh   = (const float*)d_in[8];
    const float* gp_wih   = (const float*)d_in[9];
    const float* gp_whh   = (const float*)d_in[10];
    const float* gp_bih   = (const float*)d_in[11];
    const float* gp_bhh   = (const float*)d_in[12];
    const int*   adj      = (const int*)d_in[13];
    float* out = (float*)d_out;

    unsigned long long* TB = (unsigned long long*)d_ws;             // 2*64*128*160 u64
    float* GG = (float*)(TB + 2L * B_ * NB * MROW);                 // 8192*1800 f32
    unsigned int* PK2  = (unsigned int*)(GG + 8192L * G6);           // 2*150*1800
    unsigned int* APK2 = PK2 + 2 * 150 * PK_STRIDE;                  // 8192*160
    unsigned int* BPKF = APK2 + 8192L * 160;                         // 320*512
    unsigned int* BPKL = BPKF + 320L * 512;                          // 2*1856*160
    unsigned int* PK2T = BPKL + 2L * BROWS * 160;                    // 2*1800*76
    unsigned int* APK1 = (unsigned int*)GG;                          // alias (dead before GG written)

    hipFuncSetAttribute(reinterpret_cast<const void*>(scan16),
                        hipFuncAttributeMaxDynamicSharedMemorySize, 80000);
    hipMemsetAsync(TB, 0, 2L * B_ * NB * MROW * sizeof(unsigned long long), stream);

    pack_all<<<dim3((NTOT + 255) / 256), 256, 0, stream>>>(
        gc_whh, gp_wih, features, fc1_w, gc_wih, gp_whh,
        PK2, APK1, BPKF, BPKL, PK2T, out, APK2);

    // H0 = relu(features @ fc1_w + b) -> out cols [0,300) f32 + APK2 packed f16 (MFMA)
    gemm_mf<1, 1><<<dim3(5, 64), 256, 0, stream>>>(
        APK1, 512, BPKF, 512, fc1_b, fc1_b, DH, out, OUTD, APK2, 160, DH, 32);

    for (int l = 0; l < 2; ++l) {
        gemm_mf<0, 0><<<dim3(29, 64), 256, 0, stream>>>(
            APK2, 160, BPKL + (long)l * BROWS * 160, 160,
            gc_bih + l * G3, gp_bhh + l * G3, G3,
            GG, G6, (unsigned int*)nullptr, 0, G6, 10);
        scan16<<<dim3(SLICES * B_), 512, 77824, stream>>>(
            out, GG, PK2 + (long)l * 150 * PK_STRIDE,
            PK2T + (long)l * 1800 * 76,
            gc_bhh + l * G3, gp_bih + l * G3, adj,
            gat_w + l * 2 * DH + DH,
            TB + (long)l * B_ * NB * MROW,
            APK2, l);
    }
}